// Round 10
// baseline (1960.328 us; speedup 1.0000x reference)
//
#include <hip/hip_runtime.h>
#include <hip/hip_bf16.h>

// Problem constants (from reference)
#define Bq 256
#define Iq 64
#define Tq 16
#define Vq 4096
#define Eq 256
#define Hq 256
#define NSEQ 16384
#define HSTR 264  // shorts per h-plane row in token kernel
#define CL 8      // blocks per instr cluster
#define NWAVEFL 32  // flag target: 8 blocks x 4 waves

typedef __attribute__((ext_vector_type(8))) __bf16 bf16x8;
typedef __attribute__((ext_vector_type(8))) short short8;
typedef __attribute__((ext_vector_type(4))) float f32x4;

__device__ __forceinline__ bf16x8 as_bf8(short8 v) {
    union { short8 s; bf16x8 b; } u; u.s = v; return u.b;
}
__device__ __forceinline__ float sigf(float x) {
    return __builtin_amdgcn_rcpf(1.f + __expf(-x));
}
__device__ __forceinline__ float tanh_fast(float x) {
    float e = __expf(2.f * x);
    return 1.f - 2.f * __builtin_amdgcn_rcpf(e + 1.f);
}
__device__ __forceinline__ short bf16_rne(float x) {
    unsigned u = __float_as_uint(x);
    unsigned r = (u + 0x7fffu + ((u >> 16) & 1u)) >> 16;
    return (short)r;
}
__device__ __forceinline__ float bf16f(short h) {
    return __uint_as_float(((unsigned)(unsigned short)h) << 16);
}

// ---------------------------------------------------------------------------
// K0: gate-pack Wih_tok (fp32, for k_epre) + biases.
__global__ void k_pack(const float* __restrict__ Wih_tok,
                       const float* __restrict__ b_tok,
                       const float* __restrict__ b_ins,
                       float* __restrict__ Wih4t,
                       float* __restrict__ b4t, float* __restrict__ b4i) {
    int g = blockIdx.x;          // 0..1023 original row
    int q = g >> 8;              // gate 0..3 (i,f,g,o)
    int j = g & 255;             // unit
    int k = threadIdx.x;         // 0..255
    Wih4t[(k * 256 + j) * 4 + q] = Wih_tok[g * Hq + k];
    if (k == 0) {
        b4t[j * 4 + q] = b_tok[g];
        b4i[j * 4 + q] = b_ins[g];
    }
}

// ---------------------------------------------------------------------------
// K0b: split Whh_tok / Wih_ins into bf16 hi/lo B-fragments (verified R7/R8).
__global__ void k_packB(const float* __restrict__ W0,   // Whh_tok
                        const float* __restrict__ W1,   // Wih_ins
                        short* __restrict__ B0h, short* __restrict__ B0l,
                        short* __restrict__ B1h, short* __restrict__ B1l) {
    int nt = blockIdx.x;      // 0..63 n-tile
    int kc = blockIdx.y;      // 0..7  k-chunk
    int l  = threadIdx.x;     // 0..63 lane
    int n = nt * 16 + (l & 15);
    int kb = kc * 32 + (l >> 4) * 8;
    size_t ob = ((size_t)(nt * 8 + kc) * 64 + l) * 8;
    #pragma unroll
    for (int m = 0; m < 8; ++m) {
        float v = W0[n * 256 + kb + m];
        short hi = bf16_rne(v);
        B0h[ob + m] = hi; B0l[ob + m] = bf16_rne(v - bf16f(hi));
        v = W1[n * 256 + kb + m];
        hi = bf16_rne(v);
        B1h[ob + m] = hi; B1l[ob + m] = bf16_rne(v - bf16f(hi));
    }
}

// ---------------------------------------------------------------------------
// K0b2: Whh_ins → per-cluster-block N-sliced fragments (verified R9).
// Block-local row n_local = u_local*4 + gate; slice j owns units [32j,32j+32).
__global__ void k_packB2(const float* __restrict__ W2,   // Whh_ins [1024][256]
                         short* __restrict__ B2h, short* __restrict__ B2l) {
    int bx = blockIdx.x;      // j*8 + nt
    int kc = blockIdx.y;      // 0..7
    int l  = threadIdx.x;     // 0..63
    int j  = bx >> 3, nt = bx & 7;
    int n_local = nt * 16 + (l & 15);
    int gate = n_local & 3;
    int u = j * 32 + (n_local >> 2);
    int row = gate * 256 + u;
    int kb = kc * 32 + (l >> 4) * 8;
    size_t ob = ((size_t)(bx * 8 + kc) * 64 + l) * 8;
    #pragma unroll
    for (int m = 0; m < 8; ++m) {
        float v = W2[row * 256 + kb + m];
        short hi = bf16_rne(v);
        B2h[ob + m] = hi;
        B2l[ob + m] = bf16_rne(v - bf16f(hi));
    }
}

// ---------------------------------------------------------------------------
// K0c: counting sort by length, DESCENDING.
__global__ __launch_bounds__(1024) void k_sortn(const int* __restrict__ len,
                                                int* __restrict__ perm,
                                                int n, int nbins) {
    __shared__ int cnt[65];
    __shared__ int base[65];
    int tid = threadIdx.x;
    if (tid < nbins) cnt[tid] = 0;
    __syncthreads();
    for (int i = tid; i < n; i += 1024) atomicAdd(&cnt[len[i]], 1);
    __syncthreads();
    if (tid == 0) {
        int acc = 0;
        for (int b = nbins - 1; b >= 0; --b) { base[b] = acc; acc += cnt[b]; }
    }
    __syncthreads();
    for (int i = tid; i < n; i += 1024) {
        int pos = atomicAdd(&base[len[i]], 1);
        perm[pos] = i;
    }
}

// ---------------------------------------------------------------------------
// K0d: zero hG + flags. Re-poison-safe: runs every launch.
__global__ void k_zero(int* __restrict__ p, int n) {
    int i = blockIdx.x * blockDim.x + threadIdx.x;
    if (i < n) p[i] = 0;
}

// ---------------------------------------------------------------------------
// K1: Epre4[v][j] = float4 gate pre-activations: emb[v,:]·W + b_tok
__global__ __launch_bounds__(256) void k_epre(const float* __restrict__ emb,
                                              const float4* __restrict__ Wih4t,
                                              const float4* __restrict__ b4t,
                                              float4* __restrict__ Ep4) {
    __shared__ float es[8][Eq];
    int tid = threadIdx.x;
    int v0 = blockIdx.x * 8;
    #pragma unroll
    for (int r = 0; r < 8; ++r) es[r][tid] = emb[(v0 + r) * Eq + tid];
    __syncthreads();
    float4 a[8];
    #pragma unroll
    for (int r = 0; r < 8; ++r) a[r] = make_float4(0.f, 0.f, 0.f, 0.f);
    const float4* Wp = Wih4t + tid;
    #pragma unroll 2
    for (int k = 0; k < Eq; ++k) {
        float4 wv = Wp[k * 256];
        #pragma unroll
        for (int r = 0; r < 8; ++r) {
            float e = es[r][k];
            a[r].x += wv.x * e; a[r].y += wv.y * e;
            a[r].z += wv.z * e; a[r].w += wv.w * e;
        }
    }
    float4 b4 = b4t[tid];
    #pragma unroll
    for (int r = 0; r < 8; ++r) {
        Ep4[(size_t)(v0 + r) * 256 + tid] =
            make_float4(a[r].x + b4.x, a[r].y + b4.y, a[r].z + b4.z, a[r].w + b4.w);
    }
}

// ---------------------------------------------------------------------------
// Shared MFMA kc body for the token kernel (verified R8).
#define MFMA_KC_BODY(BH, BL) { \
    bf16x8 ahi = *(const bf16x8*)(hc0 + kc * 32 + quad * 8); \
    bf16x8 alo = *(const bf16x8*)(hc1 + kc * 32 + quad * 8); \
    const short* bhb = (BH) + (size_t)(w * 4 * 8 + kc) * 512 + lane * 8; \
    const short* blb = (BL) + (size_t)(w * 4 * 8 + kc) * 512 + lane * 8; \
    _Pragma("unroll") \
    for (int g = 0; g < 4; ++g) { \
        _Pragma("unroll") \
        for (int q = 0; q < 4; ++q) { \
            bf16x8 bh = *(const bf16x8*)(bhb + g * 65536 + q * 4096); \
            bf16x8 bl = *(const bf16x8*)(blb + g * 65536 + q * 4096); \
            acc[g][q] = __builtin_amdgcn_mfma_f32_16x16x32_bf16(ahi, bh, acc[g][q], 0, 0, 0); \
            acc[g][q] = __builtin_amdgcn_mfma_f32_16x16x32_bf16(alo, bh, acc[g][q], 0, 0, 0); \
            acc[g][q] = __builtin_amdgcn_mfma_f32_16x16x32_bf16(ahi, bl, acc[g][q], 0, 0, 0); \
        } \
    } }

// ---------------------------------------------------------------------------
// K2: token LSTM via MFMA 16x16x32 bf16 split-hi/lo (unchanged from R8/R9).
__global__ __launch_bounds__(256) void k_token_mfma(
        const int* __restrict__ tokens,      // [16384][16]
        const int* __restrict__ tok_len,     // [16384]
        const int* __restrict__ perm,        // [16384] desc-sorted
        const float4* __restrict__ Ep4,      // [V*256] gate-packed (+b_tok)
        const short* __restrict__ Bhi, const short* __restrict__ Blo,   // Whh_tok
        const short* __restrict__ BXhi, const short* __restrict__ BXlo, // Wih_ins
        const float4* __restrict__ b4i,      // [256] gate-packed b_ins
        float4* __restrict__ Xp4) {          // [16384*256]
    __shared__ __align__(16) short hb[2][2][16 * HSTR];
    __shared__ int toks[16][Tq];
    __shared__ int lens[16];
    __shared__ int sid[16];
    int tid  = threadIdx.x;
    int w    = tid >> 6;
    int lane = tid & 63;
    int l15  = lane & 15;
    int quad = lane >> 4;
    int s0   = blockIdx.x * 16;

    if (tid < 16) {
        int q = perm[s0 + tid];
        sid[tid]  = q;
        lens[tid] = tok_len[q];
    }
    {
        int* hz = (int*)&hb[0][0][0];
        for (int i = tid; i < 16 * HSTR; i += 256) hz[i] = 0;
    }
    __syncthreads();
    toks[tid >> 4][tid & 15] = tokens[sid[tid >> 4] * Tq + (tid & 15)];
    int lenr[4];
    #pragma unroll
    for (int r = 0; r < 4; ++r) lenr[r] = lens[quad * 4 + r];
    int tmax = 0;
    #pragma unroll
    for (int s = 0; s < 16; ++s) tmax = max(tmax, lens[s]);
    __syncthreads();

    f32x4 acc[4][4];
    float cst[4][4], hst[4][4];
    #pragma unroll
    for (int q = 0; q < 4; ++q)
        #pragma unroll
        for (int r = 0; r < 4; ++r) { cst[q][r] = 0.f; hst[q][r] = 0.f; }
    int ubase = w * 64;

    for (int t = 0; t < tmax; ++t) {
        #pragma unroll
        for (int q = 0; q < 4; ++q) {
            int u = ubase + q * 16 + l15;
            #pragma unroll
            for (int r = 0; r < 4; ++r) {
                float4 e = Ep4[(size_t)toks[quad * 4 + r][t] * 256 + u];
                acc[0][q][r] = e.x; acc[1][q][r] = e.y;
                acc[2][q][r] = e.z; acc[3][q][r] = e.w;
            }
        }
        const short* hc0 = &hb[t & 1][0][l15 * HSTR];
        const short* hc1 = &hb[t & 1][1][l15 * HSTR];
        #pragma unroll 1
        for (int kc = 0; kc < 8; ++kc) MFMA_KC_BODY(Bhi, Blo)
        short* hn0 = &hb[(t + 1) & 1][0][0];
        short* hn1 = &hb[(t + 1) & 1][1][0];
        #pragma unroll
        for (int q = 0; q < 4; ++q) {
            int u = ubase + q * 16 + l15;
            #pragma unroll
            for (int r = 0; r < 4; ++r) {
                int s = quad * 4 + r;
                if (t < lenr[r]) {
                    float cn = sigf(acc[1][q][r]) * cst[q][r]
                             + sigf(acc[0][q][r]) * tanh_fast(acc[2][q][r]);
                    cst[q][r] = cn;
                    hst[q][r] = sigf(acc[3][q][r]) * tanh_fast(cn);
                }
                float hv = hst[q][r];
                short hi = bf16_rne(hv);
                hn0[s * HSTR + u] = hi;
                hn1[s * HSTR + u] = bf16_rne(hv - bf16f(hi));
            }
        }
        __syncthreads();
    }

    #pragma unroll
    for (int q = 0; q < 4; ++q) {
        float4 bb = b4i[ubase + q * 16 + l15];
        #pragma unroll
        for (int r = 0; r < 4; ++r) {
            acc[0][q][r] = bb.x; acc[1][q][r] = bb.y;
            acc[2][q][r] = bb.z; acc[3][q][r] = bb.w;
        }
    }
    {
        const short* hc0 = &hb[tmax & 1][0][l15 * HSTR];
        const short* hc1 = &hb[tmax & 1][1][l15 * HSTR];
        #pragma unroll 1
        for (int kc = 0; kc < 8; ++kc) MFMA_KC_BODY(BXhi, BXlo)
    }
    #pragma unroll
    for (int q = 0; q < 4; ++q) {
        int u = ubase + q * 16 + l15;
        #pragma unroll
        for (int r = 0; r < 4; ++r) {
            Xp4[(size_t)sid[quad * 4 + r] * 256 + u] =
                make_float4(acc[0][q][r], acc[1][q][r], acc[2][q][r], acc[3][q][r]);
        }
    }
}

// ---------------------------------------------------------------------------
// K3: instr LSTM, cooperative N-split v2 — LLC-atomic h exchange, NO fences.
// 16 clusters x 8 blocks x 256 thr; c = blk&15 (XCD-friendly), j = blk>>4.
// h exchanged as packed uint (lo16 = hi-plane bf16, hi16 = lo-plane bf16) via
// agent-scope atomics (execute at LLC -> cross-XCD coherent, no L2 wb/inv).
// Flags: per-WAVE release fetch_add after own stores (target 32); readers
// poll with acquire loads (no RMW storm), Xp prefetched before the poll.
__global__ __launch_bounds__(256) void k_instr_coop(
        const float* __restrict__ XpF,       // Xp4 as float [16384*1024]
        const int* __restrict__ instr_cnt,   // [256]
        const int* __restrict__ perm2,       // [256] desc-sorted
        const short* __restrict__ B2h, const short* __restrict__ B2l,
        unsigned* __restrict__ hG,           // [16][2][16][256] packed uint
        int* __restrict__ flags,             // [16][72]
        const float* __restrict__ linW,
        const float* __restrict__ linb,
        float* __restrict__ out) {           // [256]
    __shared__ __align__(16) short Bs[2][32768];   // 128 KB: hi, lo planes
    __shared__ int lens[16], sid[16];
    int tid  = threadIdx.x;
    int c    = blockIdx.x & 15;
    int j    = blockIdx.x >> 4;
    int w    = tid >> 6;
    int lane = tid & 63;
    int l15  = lane & 15;
    int quad = lane >> 4;

    if (tid < 16) {
        int q = perm2[c * 16 + tid];
        sid[tid]  = q;
        lens[tid] = instr_cnt[q];
    }
    {   // stage weight slice to LDS (once)
        const float4* s0 = (const float4*)(B2h + (size_t)j * 32768);
        const float4* s1 = (const float4*)(B2l + (size_t)j * 32768);
        float4* d0 = (float4*)&Bs[0][0];
        float4* d1 = (float4*)&Bs[1][0];
        for (int i = tid; i < 4096; i += 256) { d0[i] = s0[i]; d1[i] = s1[i]; }
    }
    __syncthreads();
    int tmax = 0;
    #pragma unroll
    for (int s = 0; s < 16; ++s) tmax = max(tmax, lens[s]);
    int lenr[4], sidr[4];
    #pragma unroll
    for (int r = 0; r < 4; ++r) { lenr[r] = lens[quad * 4 + r]; sidr[r] = sid[quad * 4 + r]; }

    float cst[2][4], hst[2][4];
    #pragma unroll
    for (int r = 0; r < 4; ++r) { cst[0][r] = cst[1][r] = 0.f; hst[0][r] = hst[1][r] = 0.f; }
    int T0 = 2 * w, T1 = 2 * w + 1;
    unsigned* hGc = hG + (size_t)c * (2 * 16 * 256);
    int* flg = flags + c * 72;
    int gbase = l15 & ~3;

    for (int t = 0; t < tmax; ++t) {
        // Xp prefetch (independent of h) BEFORE the poll
        f32x4 acc0, acc1;
        #pragma unroll
        for (int r = 0; r < 4; ++r) {
            size_t base = ((size_t)sidr[r] * Iq + t) * 1024 + j * 128;
            acc0[r] = XpF[base + T0 * 16 + l15];
            acc1[r] = XpF[base + T1 * 16 + l15];
        }
        if (t > 0) {
            while (__hip_atomic_load(&flg[t - 1], __ATOMIC_ACQUIRE,
                                     __HIP_MEMORY_SCOPE_AGENT) < NWAVEFL)
                __builtin_amdgcn_s_sleep(2);
        }
        // load all 64 packed h words (LLC atomics, all in flight)
        const unsigned* hRd = hGc + (size_t)(t & 1) * 4096 + l15 * 256;
        unsigned hpk[64];
        #pragma unroll
        for (int kc = 0; kc < 8; ++kc)
            #pragma unroll
            for (int m = 0; m < 8; ++m)
                hpk[kc * 8 + m] = __hip_atomic_load(
                    hRd + kc * 32 + quad * 8 + m,
                    __ATOMIC_RELAXED, __HIP_MEMORY_SCOPE_AGENT);
        #pragma unroll
        for (int kc = 0; kc < 8; ++kc) {
            short8 vhi, vlo;
            #pragma unroll
            for (int m = 0; m < 8; ++m) {
                unsigned u = hpk[kc * 8 + m];
                vhi[m] = (short)(u & 0xffffu);
                vlo[m] = (short)(u >> 16);
            }
            bf16x8 ahi = as_bf8(vhi), alo = as_bf8(vlo);
            bf16x8 bh0 = *(const bf16x8*)(&Bs[0][((T0 * 8 + kc) * 64 + lane) * 8]);
            bf16x8 bl0 = *(const bf16x8*)(&Bs[1][((T0 * 8 + kc) * 64 + lane) * 8]);
            bf16x8 bh1 = *(const bf16x8*)(&Bs[0][((T1 * 8 + kc) * 64 + lane) * 8]);
            bf16x8 bl1 = *(const bf16x8*)(&Bs[1][((T1 * 8 + kc) * 64 + lane) * 8]);
            acc0 = __builtin_amdgcn_mfma_f32_16x16x32_bf16(ahi, bh0, acc0, 0, 0, 0);
            acc0 = __builtin_amdgcn_mfma_f32_16x16x32_bf16(alo, bh0, acc0, 0, 0, 0);
            acc0 = __builtin_amdgcn_mfma_f32_16x16x32_bf16(ahi, bl0, acc0, 0, 0, 0);
            acc1 = __builtin_amdgcn_mfma_f32_16x16x32_bf16(ahi, bh1, acc1, 0, 0, 0);
            acc1 = __builtin_amdgcn_mfma_f32_16x16x32_bf16(alo, bh1, acc1, 0, 0, 0);
            acc1 = __builtin_amdgcn_mfma_f32_16x16x32_bf16(ahi, bl1, acc1, 0, 0, 0);
        }
        // gather 4 gates (adjacent cols) and update
        unsigned* hWr = hGc + (size_t)((t + 1) & 1) * 4096;
        #pragma unroll
        for (int r = 0; r < 4; ++r) {
            float v0 = acc0[r], v1 = acc1[r];
            float gi0 = __shfl(v0, gbase + 0, 16), gf0 = __shfl(v0, gbase + 1, 16);
            float gg0 = __shfl(v0, gbase + 2, 16), go0 = __shfl(v0, gbase + 3, 16);
            float gi1 = __shfl(v1, gbase + 0, 16), gf1 = __shfl(v1, gbase + 1, 16);
            float gg1 = __shfl(v1, gbase + 2, 16), go1 = __shfl(v1, gbase + 3, 16);
            if (t < lenr[r]) {
                float cn0 = sigf(gf0) * cst[0][r] + sigf(gi0) * tanh_fast(gg0);
                cst[0][r] = cn0;
                hst[0][r] = sigf(go0) * tanh_fast(cn0);
                float cn1 = sigf(gf1) * cst[1][r] + sigf(gi1) * tanh_fast(gg1);
                cst[1][r] = cn1;
                hst[1][r] = sigf(go1) * tanh_fast(cn1);
            }
        }
        if ((l15 & 3) == 0) {
            int u0 = 32 * j + 4 * T0 + (l15 >> 2);
            int u1 = 32 * j + 4 * T1 + (l15 >> 2);
            #pragma unroll
            for (int r = 0; r < 4; ++r) {
                int s = quad * 4 + r;
                float h0 = hst[0][r], h1 = hst[1][r];
                short h0h = bf16_rne(h0), h1h = bf16_rne(h1);
                unsigned p0 = (unsigned)(unsigned short)h0h |
                              ((unsigned)(unsigned short)bf16_rne(h0 - bf16f(h0h)) << 16);
                unsigned p1 = (unsigned)(unsigned short)h1h |
                              ((unsigned)(unsigned short)bf16_rne(h1 - bf16f(h1h)) << 16);
                __hip_atomic_store(hWr + s * 256 + u0, p0,
                                   __ATOMIC_RELAXED, __HIP_MEMORY_SCOPE_AGENT);
                __hip_atomic_store(hWr + s * 256 + u1, p1,
                                   __ATOMIC_RELAXED, __HIP_MEMORY_SCOPE_AGENT);
            }
        }
        // per-wave release: orders this wave's h stores before the flag inc
        if (lane == 0)
            __hip_atomic_fetch_add(&flg[t], 1, __ATOMIC_RELEASE,
                                   __HIP_MEMORY_SCOPE_AGENT);
    }

    // final: block j==0 computes out = linW·h + linb
    if (j == 0) {
        while (__hip_atomic_load(&flg[tmax - 1], __ATOMIC_ACQUIRE,
                                 __HIP_MEMORY_SCOPE_AGENT) < NWAVEFL)
            __builtin_amdgcn_s_sleep(2);
        const unsigned* hF = hGc + (size_t)(tmax & 1) * 4096;
        int s = tid >> 4, k0 = (tid & 15) * 16;
        float p = 0.f;
        #pragma unroll
        for (int m = 0; m < 16; ++m) {
            int u = k0 + m;
            unsigned pk = __hip_atomic_load(hF + s * 256 + u,
                                            __ATOMIC_RELAXED, __HIP_MEMORY_SCOPE_AGENT);
            float hv = bf16f((short)(pk & 0xffffu)) + bf16f((short)(pk >> 16));
            p += linW[u] * hv;
        }
        p += __shfl_down(p, 8, 16);
        p += __shfl_down(p, 4, 16);
        p += __shfl_down(p, 2, 16);
        p += __shfl_down(p, 1, 16);
        if ((tid & 15) == 0) out[sid[s]] = p + linb[0];
    }
}

// ---------------------------------------------------------------------------
extern "C" void kernel_launch(void* const* d_in, const int* in_sizes, int n_in,
                              void* d_out, int out_size, void* d_ws, size_t ws_size,
                              hipStream_t stream) {
    const int*   tokens  = (const int*)d_in[0];
    const int*   icnt    = (const int*)d_in[1];
    const int*   tcnt    = (const int*)d_in[2];
    const float* emb     = (const float*)d_in[3];
    const float* Wih_tok = (const float*)d_in[4];
    const float* Whh_tok = (const float*)d_in[5];
    const float* b_tok   = (const float*)d_in[6];
    const float* Wih_ins = (const float*)d_in[7];
    const float* Whh_ins = (const float*)d_in[8];
    const float* b_ins   = (const float*)d_in[9];
    const float* linW    = (const float*)d_in[10];
    const float* linb    = (const float*)d_in[11];
    float* out = (float*)d_out;

    float* ws_f  = (float*)d_ws;
    float* Wih4t = ws_f;                     // 262144 f
    float* b4t   = Wih4t + 262144;           // 1024 f
    float* b4i   = b4t + 1024;               // 1024 f
    int*   perm  = (int*)(b4i + 1024);       // 16384 i
    int*   perm2 = perm + 16384;             // 256 i
    int*   flags = perm2 + 256;              // 16*72 = 1152 i (+pad to 2048)
    short* Bhi   = (short*)(flags + 2048);   // 4 x 262144 shorts (token frags)
    short* Blo   = Bhi + 262144;
    short* BXhi  = Blo + 262144;
    short* BXlo  = BXhi + 262144;
    short* B2h   = BXlo + 262144;            // 2 x 262144 shorts (instr slices)
    short* B2l   = B2h + 262144;
    unsigned* hG = (unsigned*)(B2l + 262144); // 16*2*16*256 = 131072 uints
    float* Ep4   = (float*)(hG + 131072);    // 4194304 f
    float* Xp4   = Ep4 + 4194304;            // 16777216 f

    size_t need = ((char*)(Xp4 + 16777216)) - ((char*)d_ws);
    if (ws_size < need) return;  // fail loudly

    hipLaunchKernelGGL(k_pack, dim3(1024), dim3(256), 0, stream,
                       Wih_tok, b_tok, b_ins, Wih4t, b4t, b4i);
    hipLaunchKernelGGL(k_packB, dim3(64, 8), dim3(64), 0, stream,
                       Whh_tok, Wih_ins, Bhi, Blo, BXhi, BXlo);
    hipLaunchKernelGGL(k_packB2, dim3(64, 8), dim3(64), 0, stream,
                       Whh_ins, B2h, B2l);
    hipLaunchKernelGGL(k_sortn, dim3(1), dim3(1024), 0, stream, tcnt, perm, NSEQ, 17);
    hipLaunchKernelGGL(k_sortn, dim3(1), dim3(1024), 0, stream, icnt, perm2, Bq, 65);
    hipLaunchKernelGGL(k_zero, dim3(8), dim3(256), 0, stream, flags, 1152);
    hipLaunchKernelGGL(k_zero, dim3(512), dim3(256), 0, stream, (int*)hG, 131072);
    hipLaunchKernelGGL(k_epre, dim3(512), dim3(256), 0, stream,
                       emb, (const float4*)Wih4t, (const float4*)b4t, (float4*)Ep4);
    hipLaunchKernelGGL(k_token_mfma, dim3(1024), dim3(256), 0, stream,
                       tokens, tcnt, perm, (const float4*)Ep4,
                       Bhi, Blo, BXhi, BXlo, (const float4*)b4i, (float4*)Xp4);
    hipLaunchKernelGGL(k_instr_coop, dim3(128), dim3(256), 0, stream,
                       Xp4, icnt, perm2, B2h, B2l, hG, flags,
                       linW, linb, out);
}

// Round 11
// 1586.160 us; speedup vs baseline: 1.2359x; 1.2359x over previous
//
#include <hip/hip_runtime.h>
#include <hip/hip_bf16.h>

// Problem constants (from reference)
#define Bq 256
#define Iq 64
#define Tq 16
#define Vq 4096
#define Eq 256
#define Hq 256
#define NSEQ 16384
#define HSTR 264  // shorts per h-plane row in token kernel
#define CL 8      // blocks per instr cluster
// s_getreg imm: size-1=3 (<<11) | offset=0 (<<6) | HW_REG_XCC_ID=20
#define XCC_GETREG_IMM 6164

typedef __attribute__((ext_vector_type(8))) __bf16 bf16x8;
typedef __attribute__((ext_vector_type(8))) short short8;
typedef __attribute__((ext_vector_type(4))) float f32x4;

__device__ __forceinline__ bf16x8 as_bf8(short8 v) {
    union { short8 s; bf16x8 b; } u; u.s = v; return u.b;
}
__device__ __forceinline__ float sigf(float x) {
    return __builtin_amdgcn_rcpf(1.f + __expf(-x));
}
__device__ __forceinline__ float tanh_fast(float x) {
    float e = __expf(2.f * x);
    return 1.f - 2.f * __builtin_amdgcn_rcpf(e + 1.f);
}
__device__ __forceinline__ short bf16_rne(float x) {
    unsigned u = __float_as_uint(x);
    unsigned r = (u + 0x7fffu + ((u >> 16) & 1u)) >> 16;
    return (short)r;
}
__device__ __forceinline__ float bf16f(short h) {
    return __uint_as_float(((unsigned)(unsigned short)h) << 16);
}

// ---------------------------------------------------------------------------
// K0: gate-pack Wih_tok (fp32, for k_epre) + biases.
__global__ void k_pack(const float* __restrict__ Wih_tok,
                       const float* __restrict__ b_tok,
                       const float* __restrict__ b_ins,
                       float* __restrict__ Wih4t,
                       float* __restrict__ b4t, float* __restrict__ b4i) {
    int g = blockIdx.x;          // 0..1023 original row
    int q = g >> 8;              // gate 0..3 (i,f,g,o)
    int j = g & 255;             // unit
    int k = threadIdx.x;         // 0..255
    Wih4t[(k * 256 + j) * 4 + q] = Wih_tok[g * Hq + k];
    if (k == 0) {
        b4t[j * 4 + q] = b_tok[g];
        b4i[j * 4 + q] = b_ins[g];
    }
}

// ---------------------------------------------------------------------------
// K0b: split Whh_tok / Wih_ins into bf16 hi/lo B-fragments (verified R7/R8).
__global__ void k_packB(const float* __restrict__ W0,   // Whh_tok
                        const float* __restrict__ W1,   // Wih_ins
                        short* __restrict__ B0h, short* __restrict__ B0l,
                        short* __restrict__ B1h, short* __restrict__ B1l) {
    int nt = blockIdx.x;      // 0..63 n-tile
    int kc = blockIdx.y;      // 0..7  k-chunk
    int l  = threadIdx.x;     // 0..63 lane
    int n = nt * 16 + (l & 15);
    int kb = kc * 32 + (l >> 4) * 8;
    size_t ob = ((size_t)(nt * 8 + kc) * 64 + l) * 8;
    #pragma unroll
    for (int m = 0; m < 8; ++m) {
        float v = W0[n * 256 + kb + m];
        short hi = bf16_rne(v);
        B0h[ob + m] = hi; B0l[ob + m] = bf16_rne(v - bf16f(hi));
        v = W1[n * 256 + kb + m];
        hi = bf16_rne(v);
        B1h[ob + m] = hi; B1l[ob + m] = bf16_rne(v - bf16f(hi));
    }
}

// ---------------------------------------------------------------------------
// K0b2: Whh_ins → per-slice N-sliced fragments (verified R9/R10).
// Block-local row n_local = u_local*4 + gate; slice j owns units [32j,32j+32).
__global__ void k_packB2(const float* __restrict__ W2,   // Whh_ins [1024][256]
                         short* __restrict__ B2h, short* __restrict__ B2l) {
    int bx = blockIdx.x;      // j*8 + nt
    int kc = blockIdx.y;      // 0..7
    int l  = threadIdx.x;     // 0..63
    int j  = bx >> 3, nt = bx & 7;
    int n_local = nt * 16 + (l & 15);
    int gate = n_local & 3;
    int u = j * 32 + (n_local >> 2);
    int row = gate * 256 + u;
    int kb = kc * 32 + (l >> 4) * 8;
    size_t ob = ((size_t)(bx * 8 + kc) * 64 + l) * 8;
    #pragma unroll
    for (int m = 0; m < 8; ++m) {
        float v = W2[row * 256 + kb + m];
        short hi = bf16_rne(v);
        B2h[ob + m] = hi;
        B2l[ob + m] = bf16_rne(v - bf16f(hi));
    }
}

// ---------------------------------------------------------------------------
// K0c: counting sort by length, DESCENDING.
__global__ __launch_bounds__(1024) void k_sortn(const int* __restrict__ len,
                                                int* __restrict__ perm,
                                                int n, int nbins) {
    __shared__ int cnt[65];
    __shared__ int base[65];
    int tid = threadIdx.x;
    if (tid < nbins) cnt[tid] = 0;
    __syncthreads();
    for (int i = tid; i < n; i += 1024) atomicAdd(&cnt[len[i]], 1);
    __syncthreads();
    if (tid == 0) {
        int acc = 0;
        for (int b = nbins - 1; b >= 0; --b) { base[b] = acc; acc += cnt[b]; }
    }
    __syncthreads();
    for (int i = tid; i < n; i += 1024) {
        int pos = atomicAdd(&base[len[i]], 1);
        perm[pos] = i;
    }
}

// ---------------------------------------------------------------------------
// K0d: zero sync buffers. Re-poison-safe: runs every launch.
__global__ void k_zero(int* __restrict__ p, int n) {
    int i = blockIdx.x * blockDim.x + threadIdx.x;
    if (i < n) p[i] = 0;
}

// ---------------------------------------------------------------------------
// K1: Epre4[v][j] = float4 gate pre-activations: emb[v,:]·W + b_tok
__global__ __launch_bounds__(256) void k_epre(const float* __restrict__ emb,
                                              const float4* __restrict__ Wih4t,
                                              const float4* __restrict__ b4t,
                                              float4* __restrict__ Ep4) {
    __shared__ float es[8][Eq];
    int tid = threadIdx.x;
    int v0 = blockIdx.x * 8;
    #pragma unroll
    for (int r = 0; r < 8; ++r) es[r][tid] = emb[(v0 + r) * Eq + tid];
    __syncthreads();
    float4 a[8];
    #pragma unroll
    for (int r = 0; r < 8; ++r) a[r] = make_float4(0.f, 0.f, 0.f, 0.f);
    const float4* Wp = Wih4t + tid;
    #pragma unroll 2
    for (int k = 0; k < Eq; ++k) {
        float4 wv = Wp[k * 256];
        #pragma unroll
        for (int r = 0; r < 8; ++r) {
            float e = es[r][k];
            a[r].x += wv.x * e; a[r].y += wv.y * e;
            a[r].z += wv.z * e; a[r].w += wv.w * e;
        }
    }
    float4 b4 = b4t[tid];
    #pragma unroll
    for (int r = 0; r < 8; ++r) {
        Ep4[(size_t)(v0 + r) * 256 + tid] =
            make_float4(a[r].x + b4.x, a[r].y + b4.y, a[r].z + b4.z, a[r].w + b4.w);
    }
}

// ---------------------------------------------------------------------------
// Shared MFMA kc body for the token kernel (verified R8).
#define MFMA_KC_BODY(BH, BL) { \
    bf16x8 ahi = *(const bf16x8*)(hc0 + kc * 32 + quad * 8); \
    bf16x8 alo = *(const bf16x8*)(hc1 + kc * 32 + quad * 8); \
    const short* bhb = (BH) + (size_t)(w * 4 * 8 + kc) * 512 + lane * 8; \
    const short* blb = (BL) + (size_t)(w * 4 * 8 + kc) * 512 + lane * 8; \
    _Pragma("unroll") \
    for (int g = 0; g < 4; ++g) { \
        _Pragma("unroll") \
        for (int q = 0; q < 4; ++q) { \
            bf16x8 bh = *(const bf16x8*)(bhb + g * 65536 + q * 4096); \
            bf16x8 bl = *(const bf16x8*)(blb + g * 65536 + q * 4096); \
            acc[g][q] = __builtin_amdgcn_mfma_f32_16x16x32_bf16(ahi, bh, acc[g][q], 0, 0, 0); \
            acc[g][q] = __builtin_amdgcn_mfma_f32_16x16x32_bf16(alo, bh, acc[g][q], 0, 0, 0); \
            acc[g][q] = __builtin_amdgcn_mfma_f32_16x16x32_bf16(ahi, bl, acc[g][q], 0, 0, 0); \
        } \
    } }

// ---------------------------------------------------------------------------
// K2: token LSTM via MFMA 16x16x32 bf16 split-hi/lo (unchanged from R8-R10).
__global__ __launch_bounds__(256) void k_token_mfma(
        const int* __restrict__ tokens,      // [16384][16]
        const int* __restrict__ tok_len,     // [16384]
        const int* __restrict__ perm,        // [16384] desc-sorted
        const float4* __restrict__ Ep4,      // [V*256] gate-packed (+b_tok)
        const short* __restrict__ Bhi, const short* __restrict__ Blo,   // Whh_tok
        const short* __restrict__ BXhi, const short* __restrict__ BXlo, // Wih_ins
        const float4* __restrict__ b4i,      // [256] gate-packed b_ins
        float4* __restrict__ Xp4) {          // [16384*256]
    __shared__ __align__(16) short hb[2][2][16 * HSTR];
    __shared__ int toks[16][Tq];
    __shared__ int lens[16];
    __shared__ int sid[16];
    int tid  = threadIdx.x;
    int w    = tid >> 6;
    int lane = tid & 63;
    int l15  = lane & 15;
    int quad = lane >> 4;
    int s0   = blockIdx.x * 16;

    if (tid < 16) {
        int q = perm[s0 + tid];
        sid[tid]  = q;
        lens[tid] = tok_len[q];
    }
    {
        int* hz = (int*)&hb[0][0][0];
        for (int i = tid; i < 16 * HSTR; i += 256) hz[i] = 0;
    }
    __syncthreads();
    toks[tid >> 4][tid & 15] = tokens[sid[tid >> 4] * Tq + (tid & 15)];
    int lenr[4];
    #pragma unroll
    for (int r = 0; r < 4; ++r) lenr[r] = lens[quad * 4 + r];
    int tmax = 0;
    #pragma unroll
    for (int s = 0; s < 16; ++s) tmax = max(tmax, lens[s]);
    __syncthreads();

    f32x4 acc[4][4];
    float cst[4][4], hst[4][4];
    #pragma unroll
    for (int q = 0; q < 4; ++q)
        #pragma unroll
        for (int r = 0; r < 4; ++r) { cst[q][r] = 0.f; hst[q][r] = 0.f; }
    int ubase = w * 64;

    for (int t = 0; t < tmax; ++t) {
        #pragma unroll
        for (int q = 0; q < 4; ++q) {
            int u = ubase + q * 16 + l15;
            #pragma unroll
            for (int r = 0; r < 4; ++r) {
                float4 e = Ep4[(size_t)toks[quad * 4 + r][t] * 256 + u];
                acc[0][q][r] = e.x; acc[1][q][r] = e.y;
                acc[2][q][r] = e.z; acc[3][q][r] = e.w;
            }
        }
        const short* hc0 = &hb[t & 1][0][l15 * HSTR];
        const short* hc1 = &hb[t & 1][1][l15 * HSTR];
        #pragma unroll 1
        for (int kc = 0; kc < 8; ++kc) MFMA_KC_BODY(Bhi, Blo)
        short* hn0 = &hb[(t + 1) & 1][0][0];
        short* hn1 = &hb[(t + 1) & 1][1][0];
        #pragma unroll
        for (int q = 0; q < 4; ++q) {
            int u = ubase + q * 16 + l15;
            #pragma unroll
            for (int r = 0; r < 4; ++r) {
                int s = quad * 4 + r;
                if (t < lenr[r]) {
                    float cn = sigf(acc[1][q][r]) * cst[q][r]
                             + sigf(acc[0][q][r]) * tanh_fast(acc[2][q][r]);
                    cst[q][r] = cn;
                    hst[q][r] = sigf(acc[3][q][r]) * tanh_fast(cn);
                }
                float hv = hst[q][r];
                short hi = bf16_rne(hv);
                hn0[s * HSTR + u] = hi;
                hn1[s * HSTR + u] = bf16_rne(hv - bf16f(hi));
            }
        }
        __syncthreads();
    }

    #pragma unroll
    for (int q = 0; q < 4; ++q) {
        float4 bb = b4i[ubase + q * 16 + l15];
        #pragma unroll
        for (int r = 0; r < 4; ++r) {
            acc[0][q][r] = bb.x; acc[1][q][r] = bb.y;
            acc[2][q][r] = bb.z; acc[3][q][r] = bb.w;
        }
    }
    {
        const short* hc0 = &hb[tmax & 1][0][l15 * HSTR];
        const short* hc1 = &hb[tmax & 1][1][l15 * HSTR];
        #pragma unroll 1
        for (int kc = 0; kc < 8; ++kc) MFMA_KC_BODY(BXhi, BXlo)
    }
    #pragma unroll
    for (int q = 0; q < 4; ++q) {
        int u = ubase + q * 16 + l15;
        #pragma unroll
        for (int r = 0; r < 4; ++r) {
            Xp4[(size_t)sid[quad * 4 + r] * 256 + u] =
                make_float4(acc[0][q][r], acc[1][q][r], acc[2][q][r], acc[3][q][r]);
        }
    }
}

// ---------------------------------------------------------------------------
// K3: instr LSTM, intra-XCD cooperative N-split. 256 blocks x 256 thr,
// 128KB LDS each -> 1 block/CU, all resident, 32 blocks/XCD. Blocks detect
// their XCD via s_getreg(XCC_ID) and self-organize: first 16 registrants per
// XCD form 2 clusters of 8 (others exit). All cluster traffic (h, flags)
// stays in the shared per-XCD L2: plain stores (write-through L1) + volatile
// (sc0, L1-bypass) loads. No agent-scope fences/atomics in the loop.
__global__ __launch_bounds__(256) void k_instr_xcd(
        const float* __restrict__ XpF,       // Xp4 as float [16384*1024]
        const int* __restrict__ instr_cnt,   // [256]
        const int* __restrict__ perm2,       // [256] desc-sorted
        const short* __restrict__ B2h, const short* __restrict__ B2l,
        int* __restrict__ xcd_cnt,           // [8]
        int* __restrict__ flags,             // [16][65][8]
        unsigned* __restrict__ hG,           // [16][2][16][256] packed uint
        const float* __restrict__ linW,
        const float* __restrict__ linb,
        float* __restrict__ out) {           // [256]
    __shared__ __align__(16) short Bs[2][32768];   // 128 KB: hi, lo planes
    __shared__ int lens[16], sid[16], role[2];
    int tid  = threadIdx.x;
    int w    = tid >> 6;
    int lane = tid & 63;
    int l15  = lane & 15;
    int quad = lane >> 4;

    if (tid == 0) {
        int xcd = __builtin_amdgcn_s_getreg(XCC_GETREG_IMM) & 7;
        int slot = atomicAdd(&xcd_cnt[xcd], 1);
        role[0] = xcd; role[1] = slot;
    }
    __syncthreads();
    int slot = role[1];
    if (slot >= 16) return;                 // surplus block
    int c = role[0] * 2 + (slot >> 3);      // cluster (same-XCD by construction)
    int j = slot & 7;                       // N-slice within cluster

    if (tid < 16) {
        int q = perm2[c * 16 + tid];
        sid[tid]  = q;
        lens[tid] = instr_cnt[q];
    }
    {   // stage weight slice j to LDS (once)
        const float4* s0 = (const float4*)(B2h + (size_t)j * 32768);
        const float4* s1 = (const float4*)(B2l + (size_t)j * 32768);
        float4* d0 = (float4*)&Bs[0][0];
        float4* d1 = (float4*)&Bs[1][0];
        for (int i = tid; i < 4096; i += 256) { d0[i] = s0[i]; d1[i] = s1[i]; }
    }
    __syncthreads();
    int tmax = 0;
    #pragma unroll
    for (int s = 0; s < 16; ++s) tmax = max(tmax, lens[s]);
    int lenr[4], sidr[4];
    #pragma unroll
    for (int r = 0; r < 4; ++r) { lenr[r] = lens[quad * 4 + r]; sidr[r] = sid[quad * 4 + r]; }

    float cst[2][4], hst[2][4];
    #pragma unroll
    for (int r = 0; r < 4; ++r) { cst[0][r] = cst[1][r] = 0.f; hst[0][r] = hst[1][r] = 0.f; }
    int T0 = 2 * w, T1 = 2 * w + 1;
    unsigned* hGc = hG + (size_t)c * 8192;  // 2 bufs x 4096 uints
    int* flg = flags + c * 65 * 8;
    int gbase = l15 & ~3;

    for (int t = 0; t < tmax; ++t) {
        // Xp prefetch (h-independent)
        f32x4 acc0, acc1;
        #pragma unroll
        for (int r = 0; r < 4; ++r) {
            size_t base = ((size_t)sidr[r] * Iq + t) * 1024 + j * 128;
            acc0[r] = XpF[base + T0 * 16 + l15];
            acc1[r] = XpF[base + T1 * 16 + l15];
        }
        if (t > 0) {   // per-wave poll: all 8 block-flags of step t-1 (L2)
            const volatile int* fp = flg + (t - 1) * 8;
            int cap = 0;
            while (true) {
                int ok = (lane < 8) ? (fp[lane] != 0) : 1;
                if (__all(ok)) break;
                if (++cap > (1 << 22)) break;   // bounded: no hang on failure
                __builtin_amdgcn_s_sleep(1);
            }
        }
        // gather full h (16 seqs x 256 units, packed hi|lo) from L2, L1-bypass
        const volatile unsigned* hRd = hGc + (size_t)(t & 1) * 4096 + l15 * 256;
        unsigned hpk[64];
        #pragma unroll
        for (int kc = 0; kc < 8; ++kc)
            #pragma unroll
            for (int m = 0; m < 8; ++m)
                hpk[kc * 8 + m] = hRd[kc * 32 + quad * 8 + m];
        #pragma unroll
        for (int kc = 0; kc < 8; ++kc) {
            short8 vhi, vlo;
            #pragma unroll
            for (int m = 0; m < 8; ++m) {
                unsigned u = hpk[kc * 8 + m];
                vhi[m] = (short)(u & 0xffffu);
                vlo[m] = (short)(u >> 16);
            }
            bf16x8 ahi = as_bf8(vhi), alo = as_bf8(vlo);
            bf16x8 bh0 = *(const bf16x8*)(&Bs[0][((T0 * 8 + kc) * 64 + lane) * 8]);
            bf16x8 bl0 = *(const bf16x8*)(&Bs[1][((T0 * 8 + kc) * 64 + lane) * 8]);
            bf16x8 bh1 = *(const bf16x8*)(&Bs[0][((T1 * 8 + kc) * 64 + lane) * 8]);
            bf16x8 bl1 = *(const bf16x8*)(&Bs[1][((T1 * 8 + kc) * 64 + lane) * 8]);
            acc0 = __builtin_amdgcn_mfma_f32_16x16x32_bf16(ahi, bh0, acc0, 0, 0, 0);
            acc0 = __builtin_amdgcn_mfma_f32_16x16x32_bf16(alo, bh0, acc0, 0, 0, 0);
            acc0 = __builtin_amdgcn_mfma_f32_16x16x32_bf16(ahi, bl0, acc0, 0, 0, 0);
            acc1 = __builtin_amdgcn_mfma_f32_16x16x32_bf16(ahi, bh1, acc1, 0, 0, 0);
            acc1 = __builtin_amdgcn_mfma_f32_16x16x32_bf16(alo, bh1, acc1, 0, 0, 0);
            acc1 = __builtin_amdgcn_mfma_f32_16x16x32_bf16(ahi, bl1, acc1, 0, 0, 0);
        }
        // gather 4 gates (adjacent cols) and update
        volatile unsigned* hWr = hGc + (size_t)((t + 1) & 1) * 4096;
        #pragma unroll
        for (int r = 0; r < 4; ++r) {
            float v0 = acc0[r], v1 = acc1[r];
            float gi0 = __shfl(v0, gbase + 0, 16), gf0 = __shfl(v0, gbase + 1, 16);
            float gg0 = __shfl(v0, gbase + 2, 16), go0 = __shfl(v0, gbase + 3, 16);
            float gi1 = __shfl(v1, gbase + 0, 16), gf1 = __shfl(v1, gbase + 1, 16);
            float gg1 = __shfl(v1, gbase + 2, 16), go1 = __shfl(v1, gbase + 3, 16);
            if (t < lenr[r]) {
                float cn0 = sigf(gf0) * cst[0][r] + sigf(gi0) * tanh_fast(gg0);
                cst[0][r] = cn0;
                hst[0][r] = sigf(go0) * tanh_fast(cn0);
                float cn1 = sigf(gf1) * cst[1][r] + sigf(gi1) * tanh_fast(gg1);
                cst[1][r] = cn1;
                hst[1][r] = sigf(go1) * tanh_fast(cn1);
            }
        }
        if ((l15 & 3) == 0) {
            int u0 = 32 * j + 4 * T0 + (l15 >> 2);
            int u1 = 32 * j + 4 * T1 + (l15 >> 2);
            #pragma unroll
            for (int r = 0; r < 4; ++r) {
                int s = quad * 4 + r;
                float h0 = hst[0][r], h1 = hst[1][r];
                short h0h = bf16_rne(h0), h1h = bf16_rne(h1);
                unsigned p0 = (unsigned)(unsigned short)h0h |
                              ((unsigned)(unsigned short)bf16_rne(h0 - bf16f(h0h)) << 16);
                unsigned p1 = (unsigned)(unsigned short)h1h |
                              ((unsigned)(unsigned short)bf16_rne(h1 - bf16f(h1h)) << 16);
                hWr[s * 256 + u0] = p0;
                hWr[s * 256 + u1] = p1;
            }
        }
        // __syncthreads drains each wave's vmcnt -> all h stores in L2;
        // then one flag store (plain, write-through to L2).
        __syncthreads();
        if (tid == 0) *(volatile int*)(flg + t * 8 + j) = 1;
    }

    // final: wait for last step, then block j==0 computes out = linW.h + linb
    {
        const volatile int* fp = flg + (tmax - 1) * 8;
        int cap = 0;
        while (true) {
            int ok = (lane < 8) ? (fp[lane] != 0) : 1;
            if (__all(ok)) break;
            if (++cap > (1 << 22)) break;
            __builtin_amdgcn_s_sleep(1);
        }
    }
    if (j == 0) {
        const volatile unsigned* hF = hGc + (size_t)(tmax & 1) * 4096;
        int s = tid >> 4, k0 = (tid & 15) * 16;
        float p = 0.f;
        #pragma unroll
        for (int m = 0; m < 16; ++m) {
            int u = k0 + m;
            unsigned pk = hF[s * 256 + u];
            float hv = bf16f((short)(pk & 0xffffu)) + bf16f((short)(pk >> 16));
            p += linW[u] * hv;
        }
        p += __shfl_down(p, 8, 16);
        p += __shfl_down(p, 4, 16);
        p += __shfl_down(p, 2, 16);
        p += __shfl_down(p, 1, 16);
        if ((tid & 15) == 0) out[sid[s]] = p + linb[0];
    }
}

// ---------------------------------------------------------------------------
extern "C" void kernel_launch(void* const* d_in, const int* in_sizes, int n_in,
                              void* d_out, int out_size, void* d_ws, size_t ws_size,
                              hipStream_t stream) {
    const int*   tokens  = (const int*)d_in[0];
    const int*   icnt    = (const int*)d_in[1];
    const int*   tcnt    = (const int*)d_in[2];
    const float* emb     = (const float*)d_in[3];
    const float* Wih_tok = (const float*)d_in[4];
    const float* Whh_tok = (const float*)d_in[5];
    const float* b_tok   = (const float*)d_in[6];
    const float* Wih_ins = (const float*)d_in[7];
    const float* Whh_ins = (const float*)d_in[8];
    const float* b_ins   = (const float*)d_in[9];
    const float* linW    = (const float*)d_in[10];
    const float* linb    = (const float*)d_in[11];
    float* out = (float*)d_out;

    float* ws_f    = (float*)d_ws;
    float* Wih4t   = ws_f;                     // 262144 f
    float* b4t     = Wih4t + 262144;           // 1024 f
    float* b4i     = b4t + 1024;               // 1024 f
    int*   perm    = (int*)(b4i + 1024);       // 16384 i
    int*   perm2   = perm + 16384;             // 256 i
    int*   xcd_cnt = perm2 + 256;              // 8 i
    int*   flags   = xcd_cnt + 8;              // 16*65*8 = 8320 i
    int*   sync_end= flags + 8320;             // pad to 8704 total ints
    short* Bhi     = (short*)(sync_end + 376); // 4 x 262144 shorts (token frags)
    short* Blo     = Bhi + 262144;
    short* BXhi    = Blo + 262144;
    short* BXlo    = BXhi + 262144;
    short* B2h     = BXlo + 262144;            // 2 x 262144 shorts (instr slices)
    short* B2l     = B2h + 262144;
    unsigned* hG   = (unsigned*)(B2l + 262144); // 16*2*16*256 = 131072 uints
    float* Ep4     = (float*)(hG + 131072);    // 4194304 f
    float* Xp4     = Ep4 + 4194304;            // 16777216 f

    size_t need = ((char*)(Xp4 + 16777216)) - ((char*)d_ws);
    if (ws_size < need) return;  // fail loudly

    hipLaunchKernelGGL(k_pack, dim3(1024), dim3(256), 0, stream,
                       Wih_tok, b_tok, b_ins, Wih4t, b4t, b4i);
    hipLaunchKernelGGL(k_packB, dim3(64, 8), dim3(64), 0, stream,
                       Whh_tok, Wih_ins, Bhi, Blo, BXhi, BXlo);
    hipLaunchKernelGGL(k_packB2, dim3(64, 8), dim3(64), 0, stream,
                       Whh_ins, B2h, B2l);
    hipLaunchKernelGGL(k_sortn, dim3(1), dim3(1024), 0, stream, tcnt, perm, NSEQ, 17);
    hipLaunchKernelGGL(k_sortn, dim3(1), dim3(1024), 0, stream, icnt, perm2, Bq, 65);
    // zero xcd_cnt+flags (8328 ints) and hG (131072 uints)
    hipLaunchKernelGGL(k_zero, dim3(33), dim3(256), 0, stream, xcd_cnt, 8328);
    hipLaunchKernelGGL(k_zero, dim3(512), dim3(256), 0, stream, (int*)hG, 131072);
    hipLaunchKernelGGL(k_epre, dim3(512), dim3(256), 0, stream,
                       emb, (const float4*)Wih4t, (const float4*)b4t, (float4*)Ep4);
    hipLaunchKernelGGL(k_token_mfma, dim3(1024), dim3(256), 0, stream,
                       tokens, tcnt, perm, (const float4*)Ep4,
                       Bhi, Blo, BXhi, BXlo, (const float4*)b4i, (float4*)Xp4);
    hipLaunchKernelGGL(k_instr_xcd, dim3(256), dim3(256), 0, stream,
                       Xp4, icnt, perm2, B2h, B2l, xcd_cnt, flags, hG,
                       linW, linb, out);
}

// Round 12
// 918.884 us; speedup vs baseline: 2.1334x; 1.7262x over previous
//
#include <hip/hip_runtime.h>
#include <hip/hip_bf16.h>

// Problem constants (from reference)
#define Bq 256
#define Iq 64
#define Tq 16
#define Vq 4096
#define Eq 256
#define Hq 256
#define NSEQ 16384
#define HSTR 264   // shorts per h-plane row in token kernel
#define HR 272     // uints per h row in instr exchange (pad: 2-way LDS, free)
#define HBUF 4352  // 16*HR uints per h buffer
#define CL 8       // blocks per instr cluster
// s_getreg imm: size-1=3 (<<11) | offset=0 (<<6) | HW_REG_XCC_ID=20
#define XCC_GETREG_IMM 6164

typedef __attribute__((ext_vector_type(8))) __bf16 bf16x8;
typedef __attribute__((ext_vector_type(8))) short short8;
typedef __attribute__((ext_vector_type(4))) float f32x4;

__device__ __forceinline__ bf16x8 as_bf8(short8 v) {
    union { short8 s; bf16x8 b; } u; u.s = v; return u.b;
}
__device__ __forceinline__ float sigf(float x) {
    return __builtin_amdgcn_rcpf(1.f + __expf(-x));
}
__device__ __forceinline__ float tanh_fast(float x) {
    float e = __expf(2.f * x);
    return 1.f - 2.f * __builtin_amdgcn_rcpf(e + 1.f);
}
__device__ __forceinline__ short bf16_rne(float x) {
    unsigned u = __float_as_uint(x);
    unsigned r = (u + 0x7fffu + ((u >> 16) & 1u)) >> 16;
    return (short)r;
}
__device__ __forceinline__ float bf16f(short h) {
    return __uint_as_float(((unsigned)(unsigned short)h) << 16);
}
// async global->LDS, 16B per lane, sc0 (L1 bypass). Compiler tracks vmcnt;
// __syncthreads after issue guarantees completion (m97 pattern).
__device__ __forceinline__ void gl_lds16(const unsigned* g, unsigned* l) {
    __builtin_amdgcn_global_load_lds(
        (const __attribute__((address_space(1))) void*)g,
        (__attribute__((address_space(3))) void*)l, 16, 0, 1);
}

// ---------------------------------------------------------------------------
// K0: gate-pack Wih_tok (fp32, for k_epre) + biases.
__global__ void k_pack(const float* __restrict__ Wih_tok,
                       const float* __restrict__ b_tok,
                       const float* __restrict__ b_ins,
                       float* __restrict__ Wih4t,
                       float* __restrict__ b4t, float* __restrict__ b4i) {
    int g = blockIdx.x;          // 0..1023 original row
    int q = g >> 8;              // gate 0..3 (i,f,g,o)
    int j = g & 255;             // unit
    int k = threadIdx.x;         // 0..255
    Wih4t[(k * 256 + j) * 4 + q] = Wih_tok[g * Hq + k];
    if (k == 0) {
        b4t[j * 4 + q] = b_tok[g];
        b4i[j * 4 + q] = b_ins[g];
    }
}

// ---------------------------------------------------------------------------
// K0b: split Whh_tok / Wih_ins into bf16 hi/lo B-fragments (verified R7/R8).
__global__ void k_packB(const float* __restrict__ W0,   // Whh_tok
                        const float* __restrict__ W1,   // Wih_ins
                        short* __restrict__ B0h, short* __restrict__ B0l,
                        short* __restrict__ B1h, short* __restrict__ B1l) {
    int nt = blockIdx.x;      // 0..63 n-tile
    int kc = blockIdx.y;      // 0..7  k-chunk
    int l  = threadIdx.x;     // 0..63 lane
    int n = nt * 16 + (l & 15);
    int kb = kc * 32 + (l >> 4) * 8;
    size_t ob = ((size_t)(nt * 8 + kc) * 64 + l) * 8;
    #pragma unroll
    for (int m = 0; m < 8; ++m) {
        float v = W0[n * 256 + kb + m];
        short hi = bf16_rne(v);
        B0h[ob + m] = hi; B0l[ob + m] = bf16_rne(v - bf16f(hi));
        v = W1[n * 256 + kb + m];
        hi = bf16_rne(v);
        B1h[ob + m] = hi; B1l[ob + m] = bf16_rne(v - bf16f(hi));
    }
}

// ---------------------------------------------------------------------------
// K0b2: Whh_ins → per-slice N-sliced fragments (verified R9-R11).
// Block-local row n_local = u_local*4 + gate; slice j owns units [32j,32j+32).
__global__ void k_packB2(const float* __restrict__ W2,   // Whh_ins [1024][256]
                         short* __restrict__ B2h, short* __restrict__ B2l) {
    int bx = blockIdx.x;      // j*8 + nt
    int kc = blockIdx.y;      // 0..7
    int l  = threadIdx.x;     // 0..63
    int j  = bx >> 3, nt = bx & 7;
    int n_local = nt * 16 + (l & 15);
    int gate = n_local & 3;
    int u = j * 32 + (n_local >> 2);
    int row = gate * 256 + u;
    int kb = kc * 32 + (l >> 4) * 8;
    size_t ob = ((size_t)(bx * 8 + kc) * 64 + l) * 8;
    #pragma unroll
    for (int m = 0; m < 8; ++m) {
        float v = W2[row * 256 + kb + m];
        short hi = bf16_rne(v);
        B2h[ob + m] = hi;
        B2l[ob + m] = bf16_rne(v - bf16f(hi));
    }
}

// ---------------------------------------------------------------------------
// K0c: counting sort by length, DESCENDING.
__global__ __launch_bounds__(1024) void k_sortn(const int* __restrict__ len,
                                                int* __restrict__ perm,
                                                int n, int nbins) {
    __shared__ int cnt[65];
    __shared__ int base[65];
    int tid = threadIdx.x;
    if (tid < nbins) cnt[tid] = 0;
    __syncthreads();
    for (int i = tid; i < n; i += 1024) atomicAdd(&cnt[len[i]], 1);
    __syncthreads();
    if (tid == 0) {
        int acc = 0;
        for (int b = nbins - 1; b >= 0; --b) { base[b] = acc; acc += cnt[b]; }
    }
    __syncthreads();
    for (int i = tid; i < n; i += 1024) {
        int pos = atomicAdd(&base[len[i]], 1);
        perm[pos] = i;
    }
}

// ---------------------------------------------------------------------------
// K0d: zero sync buffers. Re-poison-safe: runs every launch.
__global__ void k_zero(int* __restrict__ p, int n) {
    int i = blockIdx.x * blockDim.x + threadIdx.x;
    if (i < n) p[i] = 0;
}

// ---------------------------------------------------------------------------
// K1: Epre4[v][j] = float4 gate pre-activations: emb[v,:]·W + b_tok
__global__ __launch_bounds__(256) void k_epre(const float* __restrict__ emb,
                                              const float4* __restrict__ Wih4t,
                                              const float4* __restrict__ b4t,
                                              float4* __restrict__ Ep4) {
    __shared__ float es[8][Eq];
    int tid = threadIdx.x;
    int v0 = blockIdx.x * 8;
    #pragma unroll
    for (int r = 0; r < 8; ++r) es[r][tid] = emb[(v0 + r) * Eq + tid];
    __syncthreads();
    float4 a[8];
    #pragma unroll
    for (int r = 0; r < 8; ++r) a[r] = make_float4(0.f, 0.f, 0.f, 0.f);
    const float4* Wp = Wih4t + tid;
    #pragma unroll 2
    for (int k = 0; k < Eq; ++k) {
        float4 wv = Wp[k * 256];
        #pragma unroll
        for (int r = 0; r < 8; ++r) {
            float e = es[r][k];
            a[r].x += wv.x * e; a[r].y += wv.y * e;
            a[r].z += wv.z * e; a[r].w += wv.w * e;
        }
    }
    float4 b4 = b4t[tid];
    #pragma unroll
    for (int r = 0; r < 8; ++r) {
        Ep4[(size_t)(v0 + r) * 256 + tid] =
            make_float4(a[r].x + b4.x, a[r].y + b4.y, a[r].z + b4.z, a[r].w + b4.w);
    }
}

// ---------------------------------------------------------------------------
// Shared MFMA kc body for the token kernel (verified R8).
#define MFMA_KC_BODY(BH, BL) { \
    bf16x8 ahi = *(const bf16x8*)(hc0 + kc * 32 + quad * 8); \
    bf16x8 alo = *(const bf16x8*)(hc1 + kc * 32 + quad * 8); \
    const short* bhb = (BH) + (size_t)(w * 4 * 8 + kc) * 512 + lane * 8; \
    const short* blb = (BL) + (size_t)(w * 4 * 8 + kc) * 512 + lane * 8; \
    _Pragma("unroll") \
    for (int g = 0; g < 4; ++g) { \
        _Pragma("unroll") \
        for (int q = 0; q < 4; ++q) { \
            bf16x8 bh = *(const bf16x8*)(bhb + g * 65536 + q * 4096); \
            bf16x8 bl = *(const bf16x8*)(blb + g * 65536 + q * 4096); \
            acc[g][q] = __builtin_amdgcn_mfma_f32_16x16x32_bf16(ahi, bh, acc[g][q], 0, 0, 0); \
            acc[g][q] = __builtin_amdgcn_mfma_f32_16x16x32_bf16(alo, bh, acc[g][q], 0, 0, 0); \
            acc[g][q] = __builtin_amdgcn_mfma_f32_16x16x32_bf16(ahi, bl, acc[g][q], 0, 0, 0); \
        } \
    } }

// ---------------------------------------------------------------------------
// K2: token LSTM via MFMA 16x16x32 bf16 split-hi/lo (unchanged from R8-R11).
__global__ __launch_bounds__(256) void k_token_mfma(
        const int* __restrict__ tokens,      // [16384][16]
        const int* __restrict__ tok_len,     // [16384]
        const int* __restrict__ perm,        // [16384] desc-sorted
        const float4* __restrict__ Ep4,      // [V*256] gate-packed (+b_tok)
        const short* __restrict__ Bhi, const short* __restrict__ Blo,   // Whh_tok
        const short* __restrict__ BXhi, const short* __restrict__ BXlo, // Wih_ins
        const float4* __restrict__ b4i,      // [256] gate-packed b_ins
        float4* __restrict__ Xp4) {          // [16384*256]
    __shared__ __align__(16) short hb[2][2][16 * HSTR];
    __shared__ int toks[16][Tq];
    __shared__ int lens[16];
    __shared__ int sid[16];
    int tid  = threadIdx.x;
    int w    = tid >> 6;
    int lane = tid & 63;
    int l15  = lane & 15;
    int quad = lane >> 4;
    int s0   = blockIdx.x * 16;

    if (tid < 16) {
        int q = perm[s0 + tid];
        sid[tid]  = q;
        lens[tid] = tok_len[q];
    }
    {
        int* hz = (int*)&hb[0][0][0];
        for (int i = tid; i < 16 * HSTR; i += 256) hz[i] = 0;
    }
    __syncthreads();
    toks[tid >> 4][tid & 15] = tokens[sid[tid >> 4] * Tq + (tid & 15)];
    int lenr[4];
    #pragma unroll
    for (int r = 0; r < 4; ++r) lenr[r] = lens[quad * 4 + r];
    int tmax = 0;
    #pragma unroll
    for (int s = 0; s < 16; ++s) tmax = max(tmax, lens[s]);
    __syncthreads();

    f32x4 acc[4][4];
    float cst[4][4], hst[4][4];
    #pragma unroll
    for (int q = 0; q < 4; ++q)
        #pragma unroll
        for (int r = 0; r < 4; ++r) { cst[q][r] = 0.f; hst[q][r] = 0.f; }
    int ubase = w * 64;

    for (int t = 0; t < tmax; ++t) {
        #pragma unroll
        for (int q = 0; q < 4; ++q) {
            int u = ubase + q * 16 + l15;
            #pragma unroll
            for (int r = 0; r < 4; ++r) {
                float4 e = Ep4[(size_t)toks[quad * 4 + r][t] * 256 + u];
                acc[0][q][r] = e.x; acc[1][q][r] = e.y;
                acc[2][q][r] = e.z; acc[3][q][r] = e.w;
            }
        }
        const short* hc0 = &hb[t & 1][0][l15 * HSTR];
        const short* hc1 = &hb[t & 1][1][l15 * HSTR];
        #pragma unroll 1
        for (int kc = 0; kc < 8; ++kc) MFMA_KC_BODY(Bhi, Blo)
        short* hn0 = &hb[(t + 1) & 1][0][0];
        short* hn1 = &hb[(t + 1) & 1][1][0];
        #pragma unroll
        for (int q = 0; q < 4; ++q) {
            int u = ubase + q * 16 + l15;
            #pragma unroll
            for (int r = 0; r < 4; ++r) {
                int s = quad * 4 + r;
                if (t < lenr[r]) {
                    float cn = sigf(acc[1][q][r]) * cst[q][r]
                             + sigf(acc[0][q][r]) * tanh_fast(acc[2][q][r]);
                    cst[q][r] = cn;
                    hst[q][r] = sigf(acc[3][q][r]) * tanh_fast(cn);
                }
                float hv = hst[q][r];
                short hi = bf16_rne(hv);
                hn0[s * HSTR + u] = hi;
                hn1[s * HSTR + u] = bf16_rne(hv - bf16f(hi));
            }
        }
        __syncthreads();
    }

    #pragma unroll
    for (int q = 0; q < 4; ++q) {
        float4 bb = b4i[ubase + q * 16 + l15];
        #pragma unroll
        for (int r = 0; r < 4; ++r) {
            acc[0][q][r] = bb.x; acc[1][q][r] = bb.y;
            acc[2][q][r] = bb.z; acc[3][q][r] = bb.w;
        }
    }
    {
        const short* hc0 = &hb[tmax & 1][0][l15 * HSTR];
        const short* hc1 = &hb[tmax & 1][1][l15 * HSTR];
        #pragma unroll 1
        for (int kc = 0; kc < 8; ++kc) MFMA_KC_BODY(BXhi, BXlo)
    }
    #pragma unroll
    for (int q = 0; q < 4; ++q) {
        int u = ubase + q * 16 + l15;
        #pragma unroll
        for (int r = 0; r < 4; ++r) {
            Xp4[(size_t)sid[quad * 4 + r] * 256 + u] =
                make_float4(acc[0][q][r], acc[1][q][r], acc[2][q][r], acc[3][q][r]);
        }
    }
}

// ---------------------------------------------------------------------------
// K3: instr LSTM, intra-XCD cooperative N-split v2. Same XCD self-organization
// and flag protocol as R11 (worked), but the bulk h transfer is now
// global_load_lds staging (pipelined, sc0) instead of 64 serialized volatile
// loads per lane (R11's 13.7us/step = 64 x ~300cyc waitcnt-per-volatile-load).
// h rotates through 4 buffers (stale-L1 guard) padded to HR=272 uints/row.
__global__ __launch_bounds__(256) void k_instr_xcd(
        const float* __restrict__ XpF,       // Xp4 as float [16384*1024]
        const int* __restrict__ instr_cnt,   // [256]
        const int* __restrict__ perm2,       // [256] desc-sorted
        const short* __restrict__ B2h, const short* __restrict__ B2l,
        int* __restrict__ xcd_cnt,           // [8]
        int* __restrict__ flags,             // [16][65][8]
        unsigned* __restrict__ hG,           // [16][4][16][HR] packed uint
        const float* __restrict__ linW,
        const float* __restrict__ linb,
        float* __restrict__ out) {           // [256]
    __shared__ __align__(16) short Bs[2][32768];   // 128 KB weights (hi,lo)
    __shared__ __align__(16) unsigned hS[HBUF];    // 17 KB staged h
    __shared__ int lens[16], sid[16], role[2];
    int tid  = threadIdx.x;
    int w    = tid >> 6;
    int lane = tid & 63;
    int l15  = lane & 15;
    int quad = lane >> 4;

    if (tid == 0) {
        int xcd = __builtin_amdgcn_s_getreg(XCC_GETREG_IMM) & 7;
        int slot = atomicAdd(&xcd_cnt[xcd], 1);
        role[0] = xcd; role[1] = slot;
    }
    __syncthreads();
    int slot = role[1];
    if (slot >= 16) return;                 // surplus block
    int c = role[0] * 2 + (slot >> 3);      // cluster (same-XCD by construction)
    int j = slot & 7;                       // N-slice within cluster

    if (tid < 16) {
        int q = perm2[c * 16 + tid];
        sid[tid]  = q;
        lens[tid] = instr_cnt[q];
    }
    {   // stage weight slice j to LDS (once)
        const float4* s0 = (const float4*)(B2h + (size_t)j * 32768);
        const float4* s1 = (const float4*)(B2l + (size_t)j * 32768);
        float4* d0 = (float4*)&Bs[0][0];
        float4* d1 = (float4*)&Bs[1][0];
        for (int i = tid; i < 4096; i += 256) { d0[i] = s0[i]; d1[i] = s1[i]; }
    }
    __syncthreads();
    int tmax = 0;
    #pragma unroll
    for (int s = 0; s < 16; ++s) tmax = max(tmax, lens[s]);
    int lenr[4], sidr[4];
    #pragma unroll
    for (int r = 0; r < 4; ++r) { lenr[r] = lens[quad * 4 + r]; sidr[r] = sid[quad * 4 + r]; }

    float cst[2][4], hst[2][4];
    #pragma unroll
    for (int r = 0; r < 4; ++r) { cst[0][r] = cst[1][r] = 0.f; hst[0][r] = hst[1][r] = 0.f; }
    int T0 = 2 * w, T1 = 2 * w + 1;
    unsigned* hGc = hG + (size_t)c * (4 * HBUF);
    int* flg = flags + c * 65 * 8;
    int gbase = l15 & ~3;

    for (int t = 0; t < tmax; ++t) {
        // Xp prefetch (h-independent)
        f32x4 acc0, acc1;
        #pragma unroll
        for (int r = 0; r < 4; ++r) {
            size_t base = ((size_t)sidr[r] * Iq + t) * 1024 + j * 128;
            acc0[r] = XpF[base + T0 * 16 + l15];
            acc1[r] = XpF[base + T1 * 16 + l15];
        }
        if (t > 0) {   // per-wave poll: all 8 block-flags of step t-1 (L2)
            const volatile int* fp = flg + (t - 1) * 8;
            int cap = 0;
            while (true) {
                int ok = (lane < 8) ? (fp[lane] != 0) : 1;
                if (__all(ok)) break;
                if (++cap > (1 << 22)) break;   // bounded: no hang on failure
                __builtin_amdgcn_s_sleep(1);
            }
        }
        // stage h buffer (t&3) into LDS: pipelined DMA, sc0 (L1 bypass)
        {
            const unsigned* hRdG = hGc + (size_t)(t & 3) * HBUF;
            #pragma unroll
            for (int rr = 0; rr < 4; ++rr)
                gl_lds16(hRdG + (rr * 256 + tid) * 4, hS + (rr * 256 + tid) * 4);
            if (tid < 64) gl_lds16(hRdG + (1024 + tid) * 4, hS + (1024 + tid) * 4);
        }
        __syncthreads();   // drains global_load_lds vmcnt
        const unsigned* hrow = hS + l15 * HR;
        #pragma unroll
        for (int kc = 0; kc < 8; ++kc) {
            unsigned hp[8];
            *(uint4*)&hp[0] = *(const uint4*)(hrow + kc * 32 + quad * 8);
            *(uint4*)&hp[4] = *(const uint4*)(hrow + kc * 32 + quad * 8 + 4);
            short8 vhi, vlo;
            #pragma unroll
            for (int m = 0; m < 8; ++m) {
                vhi[m] = (short)(hp[m] & 0xffffu);
                vlo[m] = (short)(hp[m] >> 16);
            }
            bf16x8 ahi = as_bf8(vhi), alo = as_bf8(vlo);
            bf16x8 bh0 = *(const bf16x8*)(&Bs[0][((T0 * 8 + kc) * 64 + lane) * 8]);
            bf16x8 bl0 = *(const bf16x8*)(&Bs[1][((T0 * 8 + kc) * 64 + lane) * 8]);
            bf16x8 bh1 = *(const bf16x8*)(&Bs[0][((T1 * 8 + kc) * 64 + lane) * 8]);
            bf16x8 bl1 = *(const bf16x8*)(&Bs[1][((T1 * 8 + kc) * 64 + lane) * 8]);
            acc0 = __builtin_amdgcn_mfma_f32_16x16x32_bf16(ahi, bh0, acc0, 0, 0, 0);
            acc0 = __builtin_amdgcn_mfma_f32_16x16x32_bf16(alo, bh0, acc0, 0, 0, 0);
            acc0 = __builtin_amdgcn_mfma_f32_16x16x32_bf16(ahi, bl0, acc0, 0, 0, 0);
            acc1 = __builtin_amdgcn_mfma_f32_16x16x32_bf16(ahi, bh1, acc1, 0, 0, 0);
            acc1 = __builtin_amdgcn_mfma_f32_16x16x32_bf16(alo, bh1, acc1, 0, 0, 0);
            acc1 = __builtin_amdgcn_mfma_f32_16x16x32_bf16(ahi, bl1, acc1, 0, 0, 0);
        }
        // gather 4 gates (adjacent cols) and update
        unsigned* hWr = hGc + (size_t)((t + 1) & 3) * HBUF;
        #pragma unroll
        for (int r = 0; r < 4; ++r) {
            float v0 = acc0[r], v1 = acc1[r];
            float gi0 = __shfl(v0, gbase + 0, 16), gf0 = __shfl(v0, gbase + 1, 16);
            float gg0 = __shfl(v0, gbase + 2, 16), go0 = __shfl(v0, gbase + 3, 16);
            float gi1 = __shfl(v1, gbase + 0, 16), gf1 = __shfl(v1, gbase + 1, 16);
            float gg1 = __shfl(v1, gbase + 2, 16), go1 = __shfl(v1, gbase + 3, 16);
            if (t < lenr[r]) {
                float cn0 = sigf(gf0) * cst[0][r] + sigf(gi0) * tanh_fast(gg0);
                cst[0][r] = cn0;
                hst[0][r] = sigf(go0) * tanh_fast(cn0);
                float cn1 = sigf(gf1) * cst[1][r] + sigf(gi1) * tanh_fast(gg1);
                cst[1][r] = cn1;
                hst[1][r] = sigf(go1) * tanh_fast(cn1);
            }
        }
        if ((l15 & 3) == 0) {   // plain stores: L1 write-through -> L2
            int u0 = 32 * j + 4 * T0 + (l15 >> 2);
            int u1 = 32 * j + 4 * T1 + (l15 >> 2);
            #pragma unroll
            for (int r = 0; r < 4; ++r) {
                int s = quad * 4 + r;
                float h0 = hst[0][r], h1 = hst[1][r];
                short h0h = bf16_rne(h0), h1h = bf16_rne(h1);
                unsigned p0 = (unsigned)(unsigned short)h0h |
                              ((unsigned)(unsigned short)bf16_rne(h0 - bf16f(h0h)) << 16);
                unsigned p1 = (unsigned)(unsigned short)h1h |
                              ((unsigned)(unsigned short)bf16_rne(h1 - bf16f(h1h)) << 16);
                hWr[s * HR + u0] = p0;
                hWr[s * HR + u1] = p1;
            }
        }
        // __syncthreads drains vmcnt (stores ACKed at L2) before the flag.
        __syncthreads();
        if (tid == 0) *(volatile int*)(flg + t * 8 + j) = 1;
    }

    // final: block j==0 stages the last h buffer and computes out = linW.h+linb
    if (j == 0) {
        const volatile int* fp = flg + (tmax - 1) * 8;
        int cap = 0;
        while (true) {
            int ok = (lane < 8) ? (fp[lane] != 0) : 1;
            if (__all(ok)) break;
            if (++cap > (1 << 22)) break;
            __builtin_amdgcn_s_sleep(1);
        }
        const unsigned* hRdG = hGc + (size_t)(tmax & 3) * HBUF;
        #pragma unroll
        for (int rr = 0; rr < 4; ++rr)
            gl_lds16(hRdG + (rr * 256 + tid) * 4, hS + (rr * 256 + tid) * 4);
        if (tid < 64) gl_lds16(hRdG + (1024 + tid) * 4, hS + (1024 + tid) * 4);
        __syncthreads();
        int s = tid >> 4, k0 = (tid & 15) * 16;
        float p = 0.f;
        #pragma unroll
        for (int m = 0; m < 16; ++m) {
            int u = k0 + m;
            unsigned pk = hS[s * HR + u];
            float hv = bf16f((short)(pk & 0xffffu)) + bf16f((short)(pk >> 16));
            p += linW[u] * hv;
        }
        p += __shfl_down(p, 8, 16);
        p += __shfl_down(p, 4, 16);
        p += __shfl_down(p, 2, 16);
        p += __shfl_down(p, 1, 16);
        if ((tid & 15) == 0) out[sid[s]] = p + linb[0];
    }
}

// ---------------------------------------------------------------------------
extern "C" void kernel_launch(void* const* d_in, const int* in_sizes, int n_in,
                              void* d_out, int out_size, void* d_ws, size_t ws_size,
                              hipStream_t stream) {
    const int*   tokens  = (const int*)d_in[0];
    const int*   icnt    = (const int*)d_in[1];
    const int*   tcnt    = (const int*)d_in[2];
    const float* emb     = (const float*)d_in[3];
    const float* Wih_tok = (const float*)d_in[4];
    const float* Whh_tok = (const float*)d_in[5];
    const float* b_tok   = (const float*)d_in[6];
    const float* Wih_ins = (const float*)d_in[7];
    const float* Whh_ins = (const float*)d_in[8];
    const float* b_ins   = (const float*)d_in[9];
    const float* linW    = (const float*)d_in[10];
    const float* linb    = (const float*)d_in[11];
    float* out = (float*)d_out;

    float* ws_f    = (float*)d_ws;
    float* Wih4t   = ws_f;                     // 262144 f
    float* b4t     = Wih4t + 262144;           // 1024 f
    float* b4i     = b4t + 1024;               // 1024 f
    int*   perm    = (int*)(b4i + 1024);       // 16384 i
    int*   perm2   = perm + 16384;             // 256 i
    int*   xcd_cnt = perm2 + 256;              // 8 i
    int*   flags   = xcd_cnt + 8;              // 16*65*8 = 8320 i
    int*   sync_end= flags + 8320;             // pad
    short* Bhi     = (short*)(sync_end + 376); // 4 x 262144 shorts (token frags)
    short* Blo     = Bhi + 262144;
    short* BXhi    = Blo + 262144;
    short* BXlo    = BXhi + 262144;
    short* B2h     = BXlo + 262144;            // 2 x 262144 shorts (instr slices)
    short* B2l     = B2h + 262144;
    unsigned* hG   = (unsigned*)(B2l + 262144); // 16*4*HBUF = 278528 uints
    float* Ep4     = (float*)(hG + 278528);    // 4194304 f
    float* Xp4     = Ep4 + 4194304;            // 16777216 f

    size_t need = ((char*)(Xp4 + 16777216)) - ((char*)d_ws);
    if (ws_size < need) return;  // fail loudly

    hipLaunchKernelGGL(k_pack, dim3(1024), dim3(256), 0, stream,
                       Wih_tok, b_tok, b_ins, Wih4t, b4t, b4i);
    hipLaunchKernelGGL(k_packB, dim3(64, 8), dim3(64), 0, stream,
                       Whh_tok, Wih_ins, Bhi, Blo, BXhi, BXlo);
    hipLaunchKernelGGL(k_packB2, dim3(64, 8), dim3(64), 0, stream,
                       Whh_ins, B2h, B2l);
    hipLaunchKernelGGL(k_sortn, dim3(1), dim3(1024), 0, stream, tcnt, perm, NSEQ, 17);
    hipLaunchKernelGGL(k_sortn, dim3(1), dim3(1024), 0, stream, icnt, perm2, Bq, 65);
    // zero xcd_cnt+flags (8328 ints) and hG (278528 uints)
    hipLaunchKernelGGL(k_zero, dim3(33), dim3(256), 0, stream, xcd_cnt, 8328);
    hipLaunchKernelGGL(k_zero, dim3(1088), dim3(256), 0, stream, (int*)hG, 278528);
    hipLaunchKernelGGL(k_epre, dim3(512), dim3(256), 0, stream,
                       emb, (const float4*)Wih4t, (const float4*)b4t, (float4*)Ep4);
    hipLaunchKernelGGL(k_token_mfma, dim3(1024), dim3(256), 0, stream,
                       tokens, tcnt, perm, (const float4*)Ep4,
                       Bhi, Blo, BXhi, BXlo, (const float4*)b4i, (float4*)Xp4);
    hipLaunchKernelGGL(k_instr_xcd, dim3(256), dim3(256), 0, stream,
                       Xp4, icnt, perm2, B2h, B2l, xcd_cnt, flags, hG,
                       linW, linb, out);
}

// Round 13
// 803.565 us; speedup vs baseline: 2.4395x; 1.1435x over previous
//
#include <hip/hip_runtime.h>
#include <hip/hip_bf16.h>

// Problem constants (from reference)
#define Bq 256
#define Iq 64
#define Tq 16
#define Vq 4096
#define Eq 256
#define Hq 256
#define NSEQ 16384
#define HSTR 264   // shorts per h-plane row in token kernel
#define HR 272     // uints per h row in instr exchange
#define HBUF 4352  // 16*HR uints per h buffer
#define CL 8       // blocks per instr cluster
// s_getreg imm: size-1=3 (<<11) | offset=0 (<<6) | HW_REG_XCC_ID=20
#define XCC_GETREG_IMM 6164

typedef __attribute__((ext_vector_type(8))) __bf16 bf16x8;
typedef __attribute__((ext_vector_type(8))) short short8;
typedef __attribute__((ext_vector_type(4))) float f32x4;

__device__ __forceinline__ bf16x8 as_bf8(short8 v) {
    union { short8 s; bf16x8 b; } u; u.s = v; return u.b;
}
__device__ __forceinline__ float sigf(float x) {
    return __builtin_amdgcn_rcpf(1.f + __expf(-x));
}
__device__ __forceinline__ float tanh_fast(float x) {
    float e = __expf(2.f * x);
    return 1.f - 2.f * __builtin_amdgcn_rcpf(e + 1.f);
}
__device__ __forceinline__ short bf16_rne(float x) {
    unsigned u = __float_as_uint(x);
    unsigned r = (u + 0x7fffu + ((u >> 16) & 1u)) >> 16;
    return (short)r;
}
__device__ __forceinline__ float bf16f(short h) {
    return __uint_as_float(((unsigned)(unsigned short)h) << 16);
}
// async global->LDS, 16B per lane, sc0 (L1 bypass).
__device__ __forceinline__ void gl_lds16(const unsigned* g, unsigned* l) {
    __builtin_amdgcn_global_load_lds(
        (const __attribute__((address_space(1))) void*)g,
        (__attribute__((address_space(3))) void*)l, 16, 0, 1);
}

// ---------------------------------------------------------------------------
// K0: gate-pack Wih_tok (fp32, for k_epre) + biases.
__global__ void k_pack(const float* __restrict__ Wih_tok,
                       const float* __restrict__ b_tok,
                       const float* __restrict__ b_ins,
                       float* __restrict__ Wih4t,
                       float* __restrict__ b4t, float* __restrict__ b4i) {
    int g = blockIdx.x;          // 0..1023 original row
    int q = g >> 8;              // gate 0..3 (i,f,g,o)
    int j = g & 255;             // unit
    int k = threadIdx.x;         // 0..255
    Wih4t[(k * 256 + j) * 4 + q] = Wih_tok[g * Hq + k];
    if (k == 0) {
        b4t[j * 4 + q] = b_tok[g];
        b4i[j * 4 + q] = b_ins[g];
    }
}

// ---------------------------------------------------------------------------
// K0b: split Whh_tok / Wih_ins into bf16 hi/lo B-fragments (verified R7/R8).
__global__ void k_packB(const float* __restrict__ W0,   // Whh_tok
                        const float* __restrict__ W1,   // Wih_ins
                        short* __restrict__ B0h, short* __restrict__ B0l,
                        short* __restrict__ B1h, short* __restrict__ B1l) {
    int nt = blockIdx.x;      // 0..63 n-tile
    int kc = blockIdx.y;      // 0..7  k-chunk
    int l  = threadIdx.x;     // 0..63 lane
    int n = nt * 16 + (l & 15);
    int kb = kc * 32 + (l >> 4) * 8;
    size_t ob = ((size_t)(nt * 8 + kc) * 64 + l) * 8;
    #pragma unroll
    for (int m = 0; m < 8; ++m) {
        float v = W0[n * 256 + kb + m];
        short hi = bf16_rne(v);
        B0h[ob + m] = hi; B0l[ob + m] = bf16_rne(v - bf16f(hi));
        v = W1[n * 256 + kb + m];
        hi = bf16_rne(v);
        B1h[ob + m] = hi; B1l[ob + m] = bf16_rne(v - bf16f(hi));
    }
}

// ---------------------------------------------------------------------------
// K0b2: Whh_ins → per-slice N-sliced fragments (verified R9-R12).
__global__ void k_packB2(const float* __restrict__ W2,   // Whh_ins [1024][256]
                         short* __restrict__ B2h, short* __restrict__ B2l) {
    int bx = blockIdx.x;      // j*8 + nt
    int kc = blockIdx.y;      // 0..7
    int l  = threadIdx.x;     // 0..63
    int j  = bx >> 3, nt = bx & 7;
    int n_local = nt * 16 + (l & 15);
    int gate = n_local & 3;
    int u = j * 32 + (n_local >> 2);
    int row = gate * 256 + u;
    int kb = kc * 32 + (l >> 4) * 8;
    size_t ob = ((size_t)(bx * 8 + kc) * 64 + l) * 8;
    #pragma unroll
    for (int m = 0; m < 8; ++m) {
        float v = W2[row * 256 + kb + m];
        short hi = bf16_rne(v);
        B2h[ob + m] = hi;
        B2l[ob + m] = bf16_rne(v - bf16f(hi));
    }
}

// ---------------------------------------------------------------------------
// K0c: counting sort by length, DESCENDING.
__global__ __launch_bounds__(1024) void k_sortn(const int* __restrict__ len,
                                                int* __restrict__ perm,
                                                int n, int nbins) {
    __shared__ int cnt[65];
    __shared__ int base[65];
    int tid = threadIdx.x;
    if (tid < nbins) cnt[tid] = 0;
    __syncthreads();
    for (int i = tid; i < n; i += 1024) atomicAdd(&cnt[len[i]], 1);
    __syncthreads();
    if (tid == 0) {
        int acc = 0;
        for (int b = nbins - 1; b >= 0; --b) { base[b] = acc; acc += cnt[b]; }
    }
    __syncthreads();
    for (int i = tid; i < n; i += 1024) {
        int pos = atomicAdd(&base[len[i]], 1);
        perm[pos] = i;
    }
}

// ---------------------------------------------------------------------------
// K0d: zero sync buffers. Re-poison-safe: runs every launch.
__global__ void k_zero(int* __restrict__ p, int n) {
    int i = blockIdx.x * blockDim.x + threadIdx.x;
    if (i < n) p[i] = 0;
}

// ---------------------------------------------------------------------------
// K1: Epre4[v][j] = float4 gate pre-activations: emb[v,:]·W + b_tok
__global__ __launch_bounds__(256) void k_epre(const float* __restrict__ emb,
                                              const float4* __restrict__ Wih4t,
                                              const float4* __restrict__ b4t,
                                              float4* __restrict__ Ep4) {
    __shared__ float es[8][Eq];
    int tid = threadIdx.x;
    int v0 = blockIdx.x * 8;
    #pragma unroll
    for (int r = 0; r < 8; ++r) es[r][tid] = emb[(v0 + r) * Eq + tid];
    __syncthreads();
    float4 a[8];
    #pragma unroll
    for (int r = 0; r < 8; ++r) a[r] = make_float4(0.f, 0.f, 0.f, 0.f);
    const float4* Wp = Wih4t + tid;
    #pragma unroll 2
    for (int k = 0; k < Eq; ++k) {
        float4 wv = Wp[k * 256];
        #pragma unroll
        for (int r = 0; r < 8; ++r) {
            float e = es[r][k];
            a[r].x += wv.x * e; a[r].y += wv.y * e;
            a[r].z += wv.z * e; a[r].w += wv.w * e;
        }
    }
    float4 b4 = b4t[tid];
    #pragma unroll
    for (int r = 0; r < 8; ++r) {
        Ep4[(size_t)(v0 + r) * 256 + tid] =
            make_float4(a[r].x + b4.x, a[r].y + b4.y, a[r].z + b4.z, a[r].w + b4.w);
    }
}

// ---------------------------------------------------------------------------
// K2: token LSTM, M=32 / 512-thr variant. 512 blocks x 8 waves.
// Wave w owns unit-tiles {w, w+8} x all 4 gates (8 n-tiles) x 2 m-tiles:
// 16 accs/lane (same 64 acc VGPRs as the verified R8 shape); every B
// fragment is loaded once and feeds both m-tiles -> B-stream bytes per
// sequence HALVED vs R8-R12 (the ~16us/MB/CU L2-port wall).
// All 4 gates of unit (ut,l15) live in-lane -> no shuffles in the update.
#define MFMA3(accv, ah, al, bh, bl) \
    accv = __builtin_amdgcn_mfma_f32_16x16x32_bf16(ah, bh, accv, 0, 0, 0); \
    accv = __builtin_amdgcn_mfma_f32_16x16x32_bf16(al, bh, accv, 0, 0, 0); \
    accv = __builtin_amdgcn_mfma_f32_16x16x32_bf16(ah, bl, accv, 0, 0, 0);

__global__ __launch_bounds__(512) void k_token_mfma(
        const int* __restrict__ tokens,      // [16384][16]
        const int* __restrict__ tok_len,     // [16384]
        const int* __restrict__ perm,        // [16384] desc-sorted
        const float4* __restrict__ Ep4,      // [V*256] gate-packed (+b_tok)
        const short* __restrict__ Bhi, const short* __restrict__ Blo,   // Whh_tok
        const short* __restrict__ BXhi, const short* __restrict__ BXlo, // Wih_ins
        const float4* __restrict__ b4i,      // [256] gate-packed b_ins
        float4* __restrict__ Xp4) {          // [16384*256]
    __shared__ __align__(16) short hb[2][2][32 * HSTR];  // 66 KB
    __shared__ int toks[32][Tq];
    __shared__ int lens[32];
    __shared__ int sid[32];
    int tid  = threadIdx.x;
    int w    = tid >> 6;     // 0..7
    int lane = tid & 63;
    int l15  = lane & 15;
    int quad = lane >> 4;
    int s0   = blockIdx.x * 32;

    if (tid < 32) {
        int q = perm[s0 + tid];
        sid[tid]  = q;
        lens[tid] = tok_len[q];
    }
    {   // zero buf 0, both planes (contiguous): 32*HSTR ints
        int* hz = (int*)&hb[0][0][0];
        for (int i = tid; i < 32 * HSTR; i += 512) hz[i] = 0;
    }
    __syncthreads();
    toks[tid >> 4][tid & 15] = tokens[sid[tid >> 4] * Tq + (tid & 15)];
    int lenr[2][4], sidr[2][4];
    #pragma unroll
    for (int mt = 0; mt < 2; ++mt)
        #pragma unroll
        for (int r = 0; r < 4; ++r) {
            lenr[mt][r] = lens[mt * 16 + quad * 4 + r];
            sidr[mt][r] = sid[mt * 16 + quad * 4 + r];
        }
    int tmax = 0;
    #pragma unroll
    for (int s = 0; s < 32; ++s) tmax = max(tmax, lens[s]);
    __syncthreads();

    f32x4 acc[2][4][2];        // [ut2][gate][mt]
    float cst[2][2][4], hst[2][2][4];   // [ut2][mt][r]
    #pragma unroll
    for (int u2 = 0; u2 < 2; ++u2)
        #pragma unroll
        for (int mt = 0; mt < 2; ++mt)
            #pragma unroll
            for (int r = 0; r < 4; ++r) { cst[u2][mt][r] = 0.f; hst[u2][mt][r] = 0.f; }

    for (int t = 0; t < tmax; ++t) {
        // C init from Epre gather (includes b_tok)
        #pragma unroll
        for (int u2 = 0; u2 < 2; ++u2) {
            int u = (w + u2 * 8) * 16 + l15;
            #pragma unroll
            for (int mt = 0; mt < 2; ++mt)
                #pragma unroll
                for (int r = 0; r < 4; ++r) {
                    float4 e = Ep4[(size_t)toks[mt * 16 + quad * 4 + r][t] * 256 + u];
                    acc[u2][0][mt][r] = e.x; acc[u2][1][mt][r] = e.y;
                    acc[u2][2][mt][r] = e.z; acc[u2][3][mt][r] = e.w;
                }
        }
        const short* hc0 = &hb[t & 1][0][0];
        const short* hc1 = &hb[t & 1][1][0];
        #pragma unroll 1
        for (int kc = 0; kc < 8; ++kc) {
            bf16x8 a0h = *(const bf16x8*)(hc0 + l15 * HSTR + kc * 32 + quad * 8);
            bf16x8 a0l = *(const bf16x8*)(hc1 + l15 * HSTR + kc * 32 + quad * 8);
            bf16x8 a1h = *(const bf16x8*)(hc0 + (16 + l15) * HSTR + kc * 32 + quad * 8);
            bf16x8 a1l = *(const bf16x8*)(hc1 + (16 + l15) * HSTR + kc * 32 + quad * 8);
            #pragma unroll
            for (int u2 = 0; u2 < 2; ++u2)
                #pragma unroll
                for (int g = 0; g < 4; ++g) {
                    size_t bo = ((size_t)((g * 16 + w + u2 * 8) * 8 + kc)) * 512 + lane * 8;
                    bf16x8 bh = *(const bf16x8*)(Bhi + bo);
                    bf16x8 bl = *(const bf16x8*)(Blo + bo);
                    MFMA3(acc[u2][g][0], a0h, a0l, bh, bl)
                    MFMA3(acc[u2][g][1], a1h, a1l, bh, bl)
                }
        }
        short* hn0 = &hb[(t + 1) & 1][0][0];
        short* hn1 = &hb[(t + 1) & 1][1][0];
        #pragma unroll
        for (int u2 = 0; u2 < 2; ++u2) {
            int u = (w + u2 * 8) * 16 + l15;
            #pragma unroll
            for (int mt = 0; mt < 2; ++mt)
                #pragma unroll
                for (int r = 0; r < 4; ++r) {
                    int s = mt * 16 + quad * 4 + r;
                    if (t < lenr[mt][r]) {
                        float cn = sigf(acc[u2][1][mt][r]) * cst[u2][mt][r]
                                 + sigf(acc[u2][0][mt][r]) * tanh_fast(acc[u2][2][mt][r]);
                        cst[u2][mt][r] = cn;
                        hst[u2][mt][r] = sigf(acc[u2][3][mt][r]) * tanh_fast(cn);
                    }
                    float hv = hst[u2][mt][r];
                    short hi = bf16_rne(hv);
                    hn0[s * HSTR + u] = hi;
                    hn1[s * HSTR + u] = bf16_rne(hv - bf16f(hi));
                }
        }
        __syncthreads();
    }

    // Xp = Wih_ins · h_final + b_ins  (one extra MFMA pass over BX frags)
    #pragma unroll
    for (int u2 = 0; u2 < 2; ++u2) {
        float4 bb = b4i[(w + u2 * 8) * 16 + l15];
        #pragma unroll
        for (int mt = 0; mt < 2; ++mt)
            #pragma unroll
            for (int r = 0; r < 4; ++r) {
                acc[u2][0][mt][r] = bb.x; acc[u2][1][mt][r] = bb.y;
                acc[u2][2][mt][r] = bb.z; acc[u2][3][mt][r] = bb.w;
            }
    }
    {
        const short* hc0 = &hb[tmax & 1][0][0];
        const short* hc1 = &hb[tmax & 1][1][0];
        #pragma unroll 1
        for (int kc = 0; kc < 8; ++kc) {
            bf16x8 a0h = *(const bf16x8*)(hc0 + l15 * HSTR + kc * 32 + quad * 8);
            bf16x8 a0l = *(const bf16x8*)(hc1 + l15 * HSTR + kc * 32 + quad * 8);
            bf16x8 a1h = *(const bf16x8*)(hc0 + (16 + l15) * HSTR + kc * 32 + quad * 8);
            bf16x8 a1l = *(const bf16x8*)(hc1 + (16 + l15) * HSTR + kc * 32 + quad * 8);
            #pragma unroll
            for (int u2 = 0; u2 < 2; ++u2)
                #pragma unroll
                for (int g = 0; g < 4; ++g) {
                    size_t bo = ((size_t)((g * 16 + w + u2 * 8) * 8 + kc)) * 512 + lane * 8;
                    bf16x8 bh = *(const bf16x8*)(BXhi + bo);
                    bf16x8 bl = *(const bf16x8*)(BXlo + bo);
                    MFMA3(acc[u2][g][0], a0h, a0l, bh, bl)
                    MFMA3(acc[u2][g][1], a1h, a1l, bh, bl)
                }
        }
    }
    #pragma unroll
    for (int u2 = 0; u2 < 2; ++u2) {
        int u = (w + u2 * 8) * 16 + l15;
        #pragma unroll
        for (int mt = 0; mt < 2; ++mt)
            #pragma unroll
            for (int r = 0; r < 4; ++r) {
                Xp4[(size_t)sidr[mt][r] * 256 + u] =
                    make_float4(acc[u2][0][mt][r], acc[u2][1][mt][r],
                                acc[u2][2][mt][r], acc[u2][3][mt][r]);
            }
    }
}

// ---------------------------------------------------------------------------
// K3: instr LSTM, intra-XCD cooperative N-split (verified R12 structure).
__global__ __launch_bounds__(256) void k_instr_xcd(
        const float* __restrict__ XpF,       // Xp4 as float [16384*1024]
        const int* __restrict__ instr_cnt,   // [256]
        const int* __restrict__ perm2,       // [256] desc-sorted
        const short* __restrict__ B2h, const short* __restrict__ B2l,
        int* __restrict__ xcd_cnt,           // [8]
        int* __restrict__ flags,             // [16][65][8]
        unsigned* __restrict__ hG,           // [16][4][16][HR] packed uint
        const float* __restrict__ linW,
        const float* __restrict__ linb,
        float* __restrict__ out) {           // [256]
    __shared__ __align__(16) short Bs[2][32768];   // 128 KB weights (hi,lo)
    __shared__ __align__(16) unsigned hS[HBUF];    // 17 KB staged h
    __shared__ int lens[16], sid[16], role[2];
    int tid  = threadIdx.x;
    int w    = tid >> 6;
    int lane = tid & 63;
    int l15  = lane & 15;
    int quad = lane >> 4;

    if (tid == 0) {
        int xcd = __builtin_amdgcn_s_getreg(XCC_GETREG_IMM) & 7;
        int slot = atomicAdd(&xcd_cnt[xcd], 1);
        role[0] = xcd; role[1] = slot;
    }
    __syncthreads();
    int slot = role[1];
    if (slot >= 16) return;                 // surplus block
    int c = role[0] * 2 + (slot >> 3);      // cluster (same-XCD by construction)
    int j = slot & 7;                       // N-slice within cluster

    if (tid < 16) {
        int q = perm2[c * 16 + tid];
        sid[tid]  = q;
        lens[tid] = instr_cnt[q];
    }
    {   // stage weight slice j to LDS (once)
        const float4* s0 = (const float4*)(B2h + (size_t)j * 32768);
        const float4* s1 = (const float4*)(B2l + (size_t)j * 32768);
        float4* d0 = (float4*)&Bs[0][0];
        float4* d1 = (float4*)&Bs[1][0];
        for (int i = tid; i < 4096; i += 256) { d0[i] = s0[i]; d1[i] = s1[i]; }
    }
    __syncthreads();
    int tmax = 0;
    #pragma unroll
    for (int s = 0; s < 16; ++s) tmax = max(tmax, lens[s]);
    int lenr[4], sidr[4];
    #pragma unroll
    for (int r = 0; r < 4; ++r) { lenr[r] = lens[quad * 4 + r]; sidr[r] = sid[quad * 4 + r]; }

    float cst[2][4], hst[2][4];
    #pragma unroll
    for (int r = 0; r < 4; ++r) { cst[0][r] = cst[1][r] = 0.f; hst[0][r] = hst[1][r] = 0.f; }
    int T0 = 2 * w, T1 = 2 * w + 1;
    unsigned* hGc = hG + (size_t)c * (4 * HBUF);
    int* flg = flags + c * 65 * 8;
    int gbase = l15 & ~3;

    for (int t = 0; t < tmax; ++t) {
        f32x4 acc0, acc1;
        #pragma unroll
        for (int r = 0; r < 4; ++r) {
            size_t base = ((size_t)sidr[r] * Iq + t) * 1024 + j * 128;
            acc0[r] = XpF[base + T0 * 16 + l15];
            acc1[r] = XpF[base + T1 * 16 + l15];
        }
        if (t > 0) {
            const volatile int* fp = flg + (t - 1) * 8;
            int cap = 0;
            while (true) {
                int ok = (lane < 8) ? (fp[lane] != 0) : 1;
                if (__all(ok)) break;
                if (++cap > (1 << 22)) break;
                __builtin_amdgcn_s_sleep(1);
            }
        }
        {
            const unsigned* hRdG = hGc + (size_t)(t & 3) * HBUF;
            #pragma unroll
            for (int rr = 0; rr < 4; ++rr)
                gl_lds16(hRdG + (rr * 256 + tid) * 4, hS + (rr * 256 + tid) * 4);
            if (tid < 64) gl_lds16(hRdG + (1024 + tid) * 4, hS + (1024 + tid) * 4);
        }
        __syncthreads();
        const unsigned* hrow = hS + l15 * HR;
        #pragma unroll
        for (int kc = 0; kc < 8; ++kc) {
            unsigned hp[8];
            *(uint4*)&hp[0] = *(const uint4*)(hrow + kc * 32 + quad * 8);
            *(uint4*)&hp[4] = *(const uint4*)(hrow + kc * 32 + quad * 8 + 4);
            short8 vhi, vlo;
            #pragma unroll
            for (int m = 0; m < 8; ++m) {
                vhi[m] = (short)(hp[m] & 0xffffu);
                vlo[m] = (short)(hp[m] >> 16);
            }
            bf16x8 ahi = as_bf8(vhi), alo = as_bf8(vlo);
            bf16x8 bh0 = *(const bf16x8*)(&Bs[0][((T0 * 8 + kc) * 64 + lane) * 8]);
            bf16x8 bl0 = *(const bf16x8*)(&Bs[1][((T0 * 8 + kc) * 64 + lane) * 8]);
            bf16x8 bh1 = *(const bf16x8*)(&Bs[0][((T1 * 8 + kc) * 64 + lane) * 8]);
            bf16x8 bl1 = *(const bf16x8*)(&Bs[1][((T1 * 8 + kc) * 64 + lane) * 8]);
            acc0 = __builtin_amdgcn_mfma_f32_16x16x32_bf16(ahi, bh0, acc0, 0, 0, 0);
            acc0 = __builtin_amdgcn_mfma_f32_16x16x32_bf16(alo, bh0, acc0, 0, 0, 0);
            acc0 = __builtin_amdgcn_mfma_f32_16x16x32_bf16(ahi, bl0, acc0, 0, 0, 0);
            acc1 = __builtin_amdgcn_mfma_f32_16x16x32_bf16(ahi, bh1, acc1, 0, 0, 0);
            acc1 = __builtin_amdgcn_mfma_f32_16x16x32_bf16(alo, bh1, acc1, 0, 0, 0);
            acc1 = __builtin_amdgcn_mfma_f32_16x16x32_bf16(ahi, bl1, acc1, 0, 0, 0);
        }
        unsigned* hWr = hGc + (size_t)((t + 1) & 3) * HBUF;
        #pragma unroll
        for (int r = 0; r < 4; ++r) {
            float v0 = acc0[r], v1 = acc1[r];
            float gi0 = __shfl(v0, gbase + 0, 16), gf0 = __shfl(v0, gbase + 1, 16);
            float gg0 = __shfl(v0, gbase + 2, 16), go0 = __shfl(v0, gbase + 3, 16);
            float gi1 = __shfl(v1, gbase + 0, 16), gf1 = __shfl(v1, gbase + 1, 16);
            float gg1 = __shfl(v1, gbase + 2, 16), go1 = __shfl(v1, gbase + 3, 16);
            if (t < lenr[r]) {
                float cn0 = sigf(gf0) * cst[0][r] + sigf(gi0) * tanh_fast(gg0);
                cst[0][r] = cn0;
                hst[0][r] = sigf(go0) * tanh_fast(cn0);
                float cn1 = sigf(gf1) * cst[1][r] + sigf(gi1) * tanh_fast(gg1);
                cst[1][r] = cn1;
                hst[1][r] = sigf(go1) * tanh_fast(cn1);
            }
        }
        if ((l15 & 3) == 0) {
            int u0 = 32 * j + 4 * T0 + (l15 >> 2);
            int u1 = 32 * j + 4 * T1 + (l15 >> 2);
            #pragma unroll
            for (int r = 0; r < 4; ++r) {
                int s = quad * 4 + r;
                float h0 = hst[0][r], h1 = hst[1][r];
                short h0h = bf16_rne(h0), h1h = bf16_rne(h1);
                unsigned p0 = (unsigned)(unsigned short)h0h |
                              ((unsigned)(unsigned short)bf16_rne(h0 - bf16f(h0h)) << 16);
                unsigned p1 = (unsigned)(unsigned short)h1h |
                              ((unsigned)(unsigned short)bf16_rne(h1 - bf16f(h1h)) << 16);
                hWr[s * HR + u0] = p0;
                hWr[s * HR + u1] = p1;
            }
        }
        __syncthreads();
        if (tid == 0) *(volatile int*)(flg + t * 8 + j) = 1;
    }

    if (j == 0) {
        const volatile int* fp = flg + (tmax - 1) * 8;
        int cap = 0;
        while (true) {
            int ok = (lane < 8) ? (fp[lane] != 0) : 1;
            if (__all(ok)) break;
            if (++cap > (1 << 22)) break;
            __builtin_amdgcn_s_sleep(1);
        }
        const unsigned* hRdG = hGc + (size_t)(tmax & 3) * HBUF;
        #pragma unroll
        for (int rr = 0; rr < 4; ++rr)
            gl_lds16(hRdG + (rr * 256 + tid) * 4, hS + (rr * 256 + tid) * 4);
        if (tid < 64) gl_lds16(hRdG + (1024 + tid) * 4, hS + (1024 + tid) * 4);
        __syncthreads();
        int s = tid >> 4, k0 = (tid & 15) * 16;
        float p = 0.f;
        #pragma unroll
        for (int m = 0; m < 16; ++m) {
            int u = k0 + m;
            unsigned pk = hS[s * HR + u];
            float hv = bf16f((short)(pk & 0xffffu)) + bf16f((short)(pk >> 16));
            p += linW[u] * hv;
        }
        p += __shfl_down(p, 8, 16);
        p += __shfl_down(p, 4, 16);
        p += __shfl_down(p, 2, 16);
        p += __shfl_down(p, 1, 16);
        if ((tid & 15) == 0) out[sid[s]] = p + linb[0];
    }
}

// ---------------------------------------------------------------------------
extern "C" void kernel_launch(void* const* d_in, const int* in_sizes, int n_in,
                              void* d_out, int out_size, void* d_ws, size_t ws_size,
                              hipStream_t stream) {
    const int*   tokens  = (const int*)d_in[0];
    const int*   icnt    = (const int*)d_in[1];
    const int*   tcnt    = (const int*)d_in[2];
    const float* emb     = (const float*)d_in[3];
    const float* Wih_tok = (const float*)d_in[4];
    const float* Whh_tok = (const float*)d_in[5];
    const float* b_tok   = (const float*)d_in[6];
    const float* Wih_ins = (const float*)d_in[7];
    const float* Whh_ins = (const float*)d_in[8];
    const float* b_ins   = (const float*)d_in[9];
    const float* linW    = (const float*)d_in[10];
    const float* linb    = (const float*)d_in[11];
    float* out = (float*)d_out;

    float* ws_f    = (float*)d_ws;
    float* Wih4t   = ws_f;                     // 262144 f
    float* b4t     = Wih4t + 262144;           // 1024 f
    float* b4i     = b4t + 1024;               // 1024 f
    int*   perm    = (int*)(b4i + 1024);       // 16384 i
    int*   perm2   = perm + 16384;             // 256 i
    int*   xcd_cnt = perm2 + 256;              // 8 i
    int*   flags   = xcd_cnt + 8;              // 16*65*8 = 8320 i
    int*   sync_end= flags + 8320;             // pad
    short* Bhi     = (short*)(sync_end + 376); // 4 x 262144 shorts (token frags)
    short* Blo     = Bhi + 262144;
    short* BXhi    = Blo + 262144;
    short* BXlo    = BXhi + 262144;
    short* B2h     = BXlo + 262144;            // 2 x 262144 shorts (instr slices)
    short* B2l     = B2h + 262144;
    unsigned* hG   = (unsigned*)(B2l + 262144); // 16*4*HBUF = 278528 uints
    float* Ep4     = (float*)(hG + 278528);    // 4194304 f
    float* Xp4     = Ep4 + 4194304;            // 16777216 f

    size_t need = ((char*)(Xp4 + 16777216)) - ((char*)d_ws);
    if (ws_size < need) return;  // fail loudly

    hipLaunchKernelGGL(k_pack, dim3(1024), dim3(256), 0, stream,
                       Wih_tok, b_tok, b_ins, Wih4t, b4t, b4i);
    hipLaunchKernelGGL(k_packB, dim3(64, 8), dim3(64), 0, stream,
                       Whh_tok, Wih_ins, Bhi, Blo, BXhi, BXlo);
    hipLaunchKernelGGL(k_packB2, dim3(64, 8), dim3(64), 0, stream,
                       Whh_ins, B2h, B2l);
    hipLaunchKernelGGL(k_sortn, dim3(1), dim3(1024), 0, stream, tcnt, perm, NSEQ, 17);
    hipLaunchKernelGGL(k_sortn, dim3(1), dim3(1024), 0, stream, icnt, perm2, Bq, 65);
    hipLaunchKernelGGL(k_zero, dim3(33), dim3(256), 0, stream, xcd_cnt, 8328);
    hipLaunchKernelGGL(k_zero, dim3(1088), dim3(256), 0, stream, (int*)hG, 278528);
    hipLaunchKernelGGL(k_epre, dim3(512), dim3(256), 0, stream,
                       emb, (const float4*)Wih4t, (const float4*)b4t, (float4*)Ep4);
    hipLaunchKernelGGL(k_token_mfma, dim3(512), dim3(512), 0, stream,
                       tokens, tcnt, perm, (const float4*)Ep4,
                       Bhi, Blo, BXhi, BXlo, (const float4*)b4i, (float4*)Xp4);
    hipLaunchKernelGGL(k_instr_xcd, dim3(256), dim3(256), 0, stream,
                       Xp4, icnt, perm2, B2h, B2l, xcd_cnt, flags, hG,
                       linW, linb, out);
}

// Round 14
// 801.557 us; speedup vs baseline: 2.4457x; 1.0025x over previous
//
#include <hip/hip_runtime.h>
#include <hip/hip_bf16.h>

// Problem constants (from reference)
#define Bq 256
#define Iq 64
#define Tq 16
#define Vq 4096
#define Eq 256
#define Hq 256
#define NSEQ 16384
#define HSTR 264   // shorts per h-plane row in token kernel
#define HR 272     // uints per h row in instr exchange
#define HBUF 4352  // 16*HR uints per h buffer
#define CL 8       // blocks per instr cluster
// s_getreg imm: size-1=3 (<<11) | offset=0 (<<6) | HW_REG_XCC_ID=20
#define XCC_GETREG_IMM 6164

typedef __attribute__((ext_vector_type(8))) __bf16 bf16x8;
typedef __attribute__((ext_vector_type(8))) short short8;
typedef __attribute__((ext_vector_type(4))) float f32x4;

__device__ __forceinline__ bf16x8 as_bf8(short8 v) {
    union { short8 s; bf16x8 b; } u; u.s = v; return u.b;
}
__device__ __forceinline__ float sigf(float x) {
    return __builtin_amdgcn_rcpf(1.f + __expf(-x));
}
__device__ __forceinline__ float tanh_fast(float x) {
    float e = __expf(2.f * x);
    return 1.f - 2.f * __builtin_amdgcn_rcpf(e + 1.f);
}
__device__ __forceinline__ short bf16_rne(float x) {
    unsigned u = __float_as_uint(x);
    unsigned r = (u + 0x7fffu + ((u >> 16) & 1u)) >> 16;
    return (short)r;
}
__device__ __forceinline__ float bf16f(short h) {
    return __uint_as_float(((unsigned)(unsigned short)h) << 16);
}
// async global->LDS, 16B per lane, sc0 (L1 bypass).
__device__ __forceinline__ void gl_lds16(const unsigned* g, unsigned* l) {
    __builtin_amdgcn_global_load_lds(
        (const __attribute__((address_space(1))) void*)g,
        (__attribute__((address_space(3))) void*)l, 16, 0, 1);
}

// ---------------------------------------------------------------------------
// K0: gate-pack Wih_tok (fp32, for k_epre) + biases.
__global__ void k_pack(const float* __restrict__ Wih_tok,
                       const float* __restrict__ b_tok,
                       const float* __restrict__ b_ins,
                       float* __restrict__ Wih4t,
                       float* __restrict__ b4t, float* __restrict__ b4i) {
    int g = blockIdx.x;          // 0..1023 original row
    int q = g >> 8;              // gate 0..3 (i,f,g,o)
    int j = g & 255;             // unit
    int k = threadIdx.x;         // 0..255
    Wih4t[(k * 256 + j) * 4 + q] = Wih_tok[g * Hq + k];
    if (k == 0) {
        b4t[j * 4 + q] = b_tok[g];
        b4i[j * 4 + q] = b_ins[g];
    }
}

// ---------------------------------------------------------------------------
// K0b: split Whh_tok / Wih_ins into bf16 hi/lo B-fragments (verified R7/R8).
__global__ void k_packB(const float* __restrict__ W0,   // Whh_tok
                        const float* __restrict__ W1,   // Wih_ins
                        short* __restrict__ B0h, short* __restrict__ B0l,
                        short* __restrict__ B1h, short* __restrict__ B1l) {
    int nt = blockIdx.x;      // 0..63 n-tile
    int kc = blockIdx.y;      // 0..7  k-chunk
    int l  = threadIdx.x;     // 0..63 lane
    int n = nt * 16 + (l & 15);
    int kb = kc * 32 + (l >> 4) * 8;
    size_t ob = ((size_t)(nt * 8 + kc) * 64 + l) * 8;
    #pragma unroll
    for (int m = 0; m < 8; ++m) {
        float v = W0[n * 256 + kb + m];
        short hi = bf16_rne(v);
        B0h[ob + m] = hi; B0l[ob + m] = bf16_rne(v - bf16f(hi));
        v = W1[n * 256 + kb + m];
        hi = bf16_rne(v);
        B1h[ob + m] = hi; B1l[ob + m] = bf16_rne(v - bf16f(hi));
    }
}

// ---------------------------------------------------------------------------
// K0b2: Whh_ins → per-slice N-sliced fragments (verified R9-R13).
__global__ void k_packB2(const float* __restrict__ W2,   // Whh_ins [1024][256]
                         short* __restrict__ B2h, short* __restrict__ B2l) {
    int bx = blockIdx.x;      // j*8 + nt
    int kc = blockIdx.y;      // 0..7
    int l  = threadIdx.x;     // 0..63
    int j  = bx >> 3, nt = bx & 7;
    int n_local = nt * 16 + (l & 15);
    int gate = n_local & 3;
    int u = j * 32 + (n_local >> 2);
    int row = gate * 256 + u;
    int kb = kc * 32 + (l >> 4) * 8;
    size_t ob = ((size_t)(bx * 8 + kc) * 64 + l) * 8;
    #pragma unroll
    for (int m = 0; m < 8; ++m) {
        float v = W2[row * 256 + kb + m];
        short hi = bf16_rne(v);
        B2h[ob + m] = hi;
        B2l[ob + m] = bf16_rne(v - bf16f(hi));
    }
}

// ---------------------------------------------------------------------------
// K0c: counting sort by length, DESCENDING.
__global__ __launch_bounds__(1024) void k_sortn(const int* __restrict__ len,
                                                int* __restrict__ perm,
                                                int n, int nbins) {
    __shared__ int cnt[65];
    __shared__ int base[65];
    int tid = threadIdx.x;
    if (tid < nbins) cnt[tid] = 0;
    __syncthreads();
    for (int i = tid; i < n; i += 1024) atomicAdd(&cnt[len[i]], 1);
    __syncthreads();
    if (tid == 0) {
        int acc = 0;
        for (int b = nbins - 1; b >= 0; --b) { base[b] = acc; acc += cnt[b]; }
    }
    __syncthreads();
    for (int i = tid; i < n; i += 1024) {
        int pos = atomicAdd(&base[len[i]], 1);
        perm[pos] = i;
    }
}

// ---------------------------------------------------------------------------
// K0d: zero sync buffers. Re-poison-safe: runs every launch.
__global__ void k_zero(int* __restrict__ p, int n) {
    int i = blockIdx.x * blockDim.x + threadIdx.x;
    if (i < n) p[i] = 0;
}

// ---------------------------------------------------------------------------
// K1: Epre4[v][j] = float4 gate pre-activations: emb[v,:]·W + b_tok
__global__ __launch_bounds__(256) void k_epre(const float* __restrict__ emb,
                                              const float4* __restrict__ Wih4t,
                                              const float4* __restrict__ b4t,
                                              float4* __restrict__ Ep4) {
    __shared__ float es[8][Eq];
    int tid = threadIdx.x;
    int v0 = blockIdx.x * 8;
    #pragma unroll
    for (int r = 0; r < 8; ++r) es[r][tid] = emb[(v0 + r) * Eq + tid];
    __syncthreads();
    float4 a[8];
    #pragma unroll
    for (int r = 0; r < 8; ++r) a[r] = make_float4(0.f, 0.f, 0.f, 0.f);
    const float4* Wp = Wih4t + tid;
    #pragma unroll 2
    for (int k = 0; k < Eq; ++k) {
        float4 wv = Wp[k * 256];
        #pragma unroll
        for (int r = 0; r < 8; ++r) {
            float e = es[r][k];
            a[r].x += wv.x * e; a[r].y += wv.y * e;
            a[r].z += wv.z * e; a[r].w += wv.w * e;
        }
    }
    float4 b4 = b4t[tid];
    #pragma unroll
    for (int r = 0; r < 8; ++r) {
        Ep4[(size_t)(v0 + r) * 256 + tid] =
            make_float4(a[r].x + b4.x, a[r].y + b4.y, a[r].z + b4.z, a[r].w + b4.w);
    }
}

// ---------------------------------------------------------------------------
// K2: token LSTM, M=32 / 512-thr, SINGLE-buffer h + 2 barriers/step.
// R13's h double-buffer pushed LDS to 70KB -> only 1 block/CU resident
// (Occupancy 22%) -> kc-loop B-loads latency-bound at ~44 GB/s/CU. Single
// buffer (36KB LDS) allows 2-3 blocks/CU: cross-block wave overlap hides
// the L2 latency. Math identical to verified R13.
#define MFMA3(accv, ah, al, bh, bl) \
    accv = __builtin_amdgcn_mfma_f32_16x16x32_bf16(ah, bh, accv, 0, 0, 0); \
    accv = __builtin_amdgcn_mfma_f32_16x16x32_bf16(al, bh, accv, 0, 0, 0); \
    accv = __builtin_amdgcn_mfma_f32_16x16x32_bf16(ah, bl, accv, 0, 0, 0);

__global__ __launch_bounds__(512) void k_token_mfma(
        const int* __restrict__ tokens,      // [16384][16]
        const int* __restrict__ tok_len,     // [16384]
        const int* __restrict__ perm,        // [16384] desc-sorted
        const float4* __restrict__ Ep4,      // [V*256] gate-packed (+b_tok)
        const short* __restrict__ Bhi, const short* __restrict__ Blo,   // Whh_tok
        const short* __restrict__ BXhi, const short* __restrict__ BXlo, // Wih_ins
        const float4* __restrict__ b4i,      // [256] gate-packed b_ins
        float4* __restrict__ Xp4) {          // [16384*256]
    __shared__ __align__(16) short hb[2][32 * HSTR];  // [plane][row] 33.8 KB
    __shared__ int toks[32][Tq];
    __shared__ int lens[32];
    __shared__ int sid[32];
    int tid  = threadIdx.x;
    int w    = tid >> 6;     // 0..7
    int lane = tid & 63;
    int l15  = lane & 15;
    int quad = lane >> 4;
    int s0   = blockIdx.x * 32;

    if (tid < 32) {
        int q = perm[s0 + tid];
        sid[tid]  = q;
        lens[tid] = tok_len[q];
    }
    {   // zero both planes: 32*HSTR ints total
        int* hz = (int*)&hb[0][0];
        for (int i = tid; i < 32 * HSTR; i += 512) hz[i] = 0;
    }
    __syncthreads();
    toks[tid >> 4][tid & 15] = tokens[sid[tid >> 4] * Tq + (tid & 15)];
    int lenr[2][4], sidr[2][4];
    #pragma unroll
    for (int mt = 0; mt < 2; ++mt)
        #pragma unroll
        for (int r = 0; r < 4; ++r) {
            lenr[mt][r] = lens[mt * 16 + quad * 4 + r];
            sidr[mt][r] = sid[mt * 16 + quad * 4 + r];
        }
    int tmax = 0;
    #pragma unroll
    for (int s = 0; s < 32; ++s) tmax = max(tmax, lens[s]);
    __syncthreads();

    f32x4 acc[2][4][2];        // [ut2][gate][mt]
    float cst[2][2][4], hst[2][2][4];   // [ut2][mt][r]
    #pragma unroll
    for (int u2 = 0; u2 < 2; ++u2)
        #pragma unroll
        for (int mt = 0; mt < 2; ++mt)
            #pragma unroll
            for (int r = 0; r < 4; ++r) { cst[u2][mt][r] = 0.f; hst[u2][mt][r] = 0.f; }

    for (int t = 0; t < tmax; ++t) {
        // C init from Epre gather (includes b_tok)
        #pragma unroll
        for (int u2 = 0; u2 < 2; ++u2) {
            int u = (w + u2 * 8) * 16 + l15;
            #pragma unroll
            for (int mt = 0; mt < 2; ++mt)
                #pragma unroll
                for (int r = 0; r < 4; ++r) {
                    float4 e = Ep4[(size_t)toks[mt * 16 + quad * 4 + r][t] * 256 + u];
                    acc[u2][0][mt][r] = e.x; acc[u2][1][mt][r] = e.y;
                    acc[u2][2][mt][r] = e.z; acc[u2][3][mt][r] = e.w;
                }
        }
        const short* hc0 = &hb[0][0];
        const short* hc1 = &hb[1][0];
        #pragma unroll 1
        for (int kc = 0; kc < 8; ++kc) {
            bf16x8 a0h = *(const bf16x8*)(hc0 + l15 * HSTR + kc * 32 + quad * 8);
            bf16x8 a0l = *(const bf16x8*)(hc1 + l15 * HSTR + kc * 32 + quad * 8);
            bf16x8 a1h = *(const bf16x8*)(hc0 + (16 + l15) * HSTR + kc * 32 + quad * 8);
            bf16x8 a1l = *(const bf16x8*)(hc1 + (16 + l15) * HSTR + kc * 32 + quad * 8);
            #pragma unroll
            for (int u2 = 0; u2 < 2; ++u2)
                #pragma unroll
                for (int g = 0; g < 4; ++g) {
                    size_t bo = ((size_t)((g * 16 + w + u2 * 8) * 8 + kc)) * 512 + lane * 8;
                    bf16x8 bh = *(const bf16x8*)(Bhi + bo);
                    bf16x8 bl = *(const bf16x8*)(Blo + bo);
                    MFMA3(acc[u2][g][0], a0h, a0l, bh, bl)
                    MFMA3(acc[u2][g][1], a1h, a1l, bh, bl)
                }
        }
        __syncthreads();   // all lanes done READING hb
        #pragma unroll
        for (int u2 = 0; u2 < 2; ++u2) {
            int u = (w + u2 * 8) * 16 + l15;
            #pragma unroll
            for (int mt = 0; mt < 2; ++mt)
                #pragma unroll
                for (int r = 0; r < 4; ++r) {
                    int s = mt * 16 + quad * 4 + r;
                    if (t < lenr[mt][r]) {
                        float cn = sigf(acc[u2][1][mt][r]) * cst[u2][mt][r]
                                 + sigf(acc[u2][0][mt][r]) * tanh_fast(acc[u2][2][mt][r]);
                        cst[u2][mt][r] = cn;
                        hst[u2][mt][r] = sigf(acc[u2][3][mt][r]) * tanh_fast(cn);
                    }
                    float hv = hst[u2][mt][r];
                    short hi = bf16_rne(hv);
                    hb[0][s * HSTR + u] = hi;
                    hb[1][s * HSTR + u] = bf16_rne(hv - bf16f(hi));
                }
        }
        __syncthreads();   // writes visible for next step
    }

    // Xp = Wih_ins · h_final + b_ins  (one extra MFMA pass over BX frags)
    #pragma unroll
    for (int u2 = 0; u2 < 2; ++u2) {
        float4 bb = b4i[(w + u2 * 8) * 16 + l15];
        #pragma unroll
        for (int mt = 0; mt < 2; ++mt)
            #pragma unroll
            for (int r = 0; r < 4; ++r) {
                acc[u2][0][mt][r] = bb.x; acc[u2][1][mt][r] = bb.y;
                acc[u2][2][mt][r] = bb.z; acc[u2][3][mt][r] = bb.w;
            }
    }
    {
        const short* hc0 = &hb[0][0];
        const short* hc1 = &hb[1][0];
        #pragma unroll 1
        for (int kc = 0; kc < 8; ++kc) {
            bf16x8 a0h = *(const bf16x8*)(hc0 + l15 * HSTR + kc * 32 + quad * 8);
            bf16x8 a0l = *(const bf16x8*)(hc1 + l15 * HSTR + kc * 32 + quad * 8);
            bf16x8 a1h = *(const bf16x8*)(hc0 + (16 + l15) * HSTR + kc * 32 + quad * 8);
            bf16x8 a1l = *(const bf16x8*)(hc1 + (16 + l15) * HSTR + kc * 32 + quad * 8);
            #pragma unroll
            for (int u2 = 0; u2 < 2; ++u2)
                #pragma unroll
                for (int g = 0; g < 4; ++g) {
                    size_t bo = ((size_t)((g * 16 + w + u2 * 8) * 8 + kc)) * 512 + lane * 8;
                    bf16x8 bh = *(const bf16x8*)(BXhi + bo);
                    bf16x8 bl = *(const bf16x8*)(BXlo + bo);
                    MFMA3(acc[u2][g][0], a0h, a0l, bh, bl)
                    MFMA3(acc[u2][g][1], a1h, a1l, bh, bl)
                }
        }
    }
    #pragma unroll
    for (int u2 = 0; u2 < 2; ++u2) {
        int u = (w + u2 * 8) * 16 + l15;
        #pragma unroll
        for (int mt = 0; mt < 2; ++mt)
            #pragma unroll
            for (int r = 0; r < 4; ++r) {
                Xp4[(size_t)sidr[mt][r] * 256 + u] =
                    make_float4(acc[u2][0][mt][r], acc[u2][1][mt][r],
                                acc[u2][2][mt][r], acc[u2][3][mt][r]);
            }
    }
}

// ---------------------------------------------------------------------------
// K3: instr LSTM, intra-XCD cooperative N-split (verified R12/R13 structure).
__global__ __launch_bounds__(256) void k_instr_xcd(
        const float* __restrict__ XpF,       // Xp4 as float [16384*1024]
        const int* __restrict__ instr_cnt,   // [256]
        const int* __restrict__ perm2,       // [256] desc-sorted
        const short* __restrict__ B2h, const short* __restrict__ B2l,
        int* __restrict__ xcd_cnt,           // [8]
        int* __restrict__ flags,             // [16][65][8]
        unsigned* __restrict__ hG,           // [16][4][16][HR] packed uint
        const float* __restrict__ linW,
        const float* __restrict__ linb,
        float* __restrict__ out) {           // [256]
    __shared__ __align__(16) short Bs[2][32768];   // 128 KB weights (hi,lo)
    __shared__ __align__(16) unsigned hS[HBUF];    // 17 KB staged h
    __shared__ int lens[16], sid[16], role[2];
    int tid  = threadIdx.x;
    int w    = tid >> 6;
    int lane = tid & 63;
    int l15  = lane & 15;
    int quad = lane >> 4;

    if (tid == 0) {
        int xcd = __builtin_amdgcn_s_getreg(XCC_GETREG_IMM) & 7;
        int slot = atomicAdd(&xcd_cnt[xcd], 1);
        role[0] = xcd; role[1] = slot;
    }
    __syncthreads();
    int slot = role[1];
    if (slot >= 16) return;                 // surplus block
    int c = role[0] * 2 + (slot >> 3);      // cluster (same-XCD by construction)
    int j = slot & 7;                       // N-slice within cluster

    if (tid < 16) {
        int q = perm2[c * 16 + tid];
        sid[tid]  = q;
        lens[tid] = instr_cnt[q];
    }
    {   // stage weight slice j to LDS (once)
        const float4* s0 = (const float4*)(B2h + (size_t)j * 32768);
        const float4* s1 = (const float4*)(B2l + (size_t)j * 32768);
        float4* d0 = (float4*)&Bs[0][0];
        float4* d1 = (float4*)&Bs[1][0];
        for (int i = tid; i < 4096; i += 256) { d0[i] = s0[i]; d1[i] = s1[i]; }
    }
    __syncthreads();
    int tmax = 0;
    #pragma unroll
    for (int s = 0; s < 16; ++s) tmax = max(tmax, lens[s]);
    int lenr[4], sidr[4];
    #pragma unroll
    for (int r = 0; r < 4; ++r) { lenr[r] = lens[quad * 4 + r]; sidr[r] = sid[quad * 4 + r]; }

    float cst[2][4], hst[2][4];
    #pragma unroll
    for (int r = 0; r < 4; ++r) { cst[0][r] = cst[1][r] = 0.f; hst[0][r] = hst[1][r] = 0.f; }
    int T0 = 2 * w, T1 = 2 * w + 1;
    unsigned* hGc = hG + (size_t)c * (4 * HBUF);
    int* flg = flags + c * 65 * 8;
    int gbase = l15 & ~3;

    for (int t = 0; t < tmax; ++t) {
        f32x4 acc0, acc1;
        #pragma unroll
        for (int r = 0; r < 4; ++r) {
            size_t base = ((size_t)sidr[r] * Iq + t) * 1024 + j * 128;
            acc0[r] = XpF[base + T0 * 16 + l15];
            acc1[r] = XpF[base + T1 * 16 + l15];
        }
        if (t > 0) {
            const volatile int* fp = flg + (t - 1) * 8;
            int cap = 0;
            while (true) {
                int ok = (lane < 8) ? (fp[lane] != 0) : 1;
                if (__all(ok)) break;
                if (++cap > (1 << 22)) break;
                __builtin_amdgcn_s_sleep(1);
            }
        }
        {
            const unsigned* hRdG = hGc + (size_t)(t & 3) * HBUF;
            #pragma unroll
            for (int rr = 0; rr < 4; ++rr)
                gl_lds16(hRdG + (rr * 256 + tid) * 4, hS + (rr * 256 + tid) * 4);
            if (tid < 64) gl_lds16(hRdG + (1024 + tid) * 4, hS + (1024 + tid) * 4);
        }
        __syncthreads();
        const unsigned* hrow = hS + l15 * HR;
        #pragma unroll
        for (int kc = 0; kc < 8; ++kc) {
            unsigned hp[8];
            *(uint4*)&hp[0] = *(const uint4*)(hrow + kc * 32 + quad * 8);
            *(uint4*)&hp[4] = *(const uint4*)(hrow + kc * 32 + quad * 8 + 4);
            short8 vhi, vlo;
            #pragma unroll
            for (int m = 0; m < 8; ++m) {
                vhi[m] = (short)(hp[m] & 0xffffu);
                vlo[m] = (short)(hp[m] >> 16);
            }
            bf16x8 ahi = as_bf8(vhi), alo = as_bf8(vlo);
            bf16x8 bh0 = *(const bf16x8*)(&Bs[0][((T0 * 8 + kc) * 64 + lane) * 8]);
            bf16x8 bl0 = *(const bf16x8*)(&Bs[1][((T0 * 8 + kc) * 64 + lane) * 8]);
            bf16x8 bh1 = *(const bf16x8*)(&Bs[0][((T1 * 8 + kc) * 64 + lane) * 8]);
            bf16x8 bl1 = *(const bf16x8*)(&Bs[1][((T1 * 8 + kc) * 64 + lane) * 8]);
            acc0 = __builtin_amdgcn_mfma_f32_16x16x32_bf16(ahi, bh0, acc0, 0, 0, 0);
            acc0 = __builtin_amdgcn_mfma_f32_16x16x32_bf16(alo, bh0, acc0, 0, 0, 0);
            acc0 = __builtin_amdgcn_mfma_f32_16x16x32_bf16(ahi, bl0, acc0, 0, 0, 0);
            acc1 = __builtin_amdgcn_mfma_f32_16x16x32_bf16(ahi, bh1, acc1, 0, 0, 0);
            acc1 = __builtin_amdgcn_mfma_f32_16x16x32_bf16(alo, bh1, acc1, 0, 0, 0);
            acc1 = __builtin_amdgcn_mfma_f32_16x16x32_bf16(ahi, bl1, acc1, 0, 0, 0);
        }
        unsigned* hWr = hGc + (size_t)((t + 1) & 3) * HBUF;
        #pragma unroll
        for (int r = 0; r < 4; ++r) {
            float v0 = acc0[r], v1 = acc1[r];
            float gi0 = __shfl(v0, gbase + 0, 16), gf0 = __shfl(v0, gbase + 1, 16);
            float gg0 = __shfl(v0, gbase + 2, 16), go0 = __shfl(v0, gbase + 3, 16);
            float gi1 = __shfl(v1, gbase + 0, 16), gf1 = __shfl(v1, gbase + 1, 16);
            float gg1 = __shfl(v1, gbase + 2, 16), go1 = __shfl(v1, gbase + 3, 16);
            if (t < lenr[r]) {
                float cn0 = sigf(gf0) * cst[0][r] + sigf(gi0) * tanh_fast(gg0);
                cst[0][r] = cn0;
                hst[0][r] = sigf(go0) * tanh_fast(cn0);
                float cn1 = sigf(gf1) * cst[1][r] + sigf(gi1) * tanh_fast(gg1);
                cst[1][r] = cn1;
                hst[1][r] = sigf(go1) * tanh_fast(cn1);
            }
        }
        if ((l15 & 3) == 0) {
            int u0 = 32 * j + 4 * T0 + (l15 >> 2);
            int u1 = 32 * j + 4 * T1 + (l15 >> 2);
            #pragma unroll
            for (int r = 0; r < 4; ++r) {
                int s = quad * 4 + r;
                float h0 = hst[0][r], h1 = hst[1][r];
                short h0h = bf16_rne(h0), h1h = bf16_rne(h1);
                unsigned p0 = (unsigned)(unsigned short)h0h |
                              ((unsigned)(unsigned short)bf16_rne(h0 - bf16f(h0h)) << 16);
                unsigned p1 = (unsigned)(unsigned short)h1h |
                              ((unsigned)(unsigned short)bf16_rne(h1 - bf16f(h1h)) << 16);
                hWr[s * HR + u0] = p0;
                hWr[s * HR + u1] = p1;
            }
        }
        __syncthreads();
        if (tid == 0) *(volatile int*)(flg + t * 8 + j) = 1;
    }

    if (j == 0) {
        const volatile int* fp = flg + (tmax - 1) * 8;
        int cap = 0;
        while (true) {
            int ok = (lane < 8) ? (fp[lane] != 0) : 1;
            if (__all(ok)) break;
            if (++cap > (1 << 22)) break;
            __builtin_amdgcn_s_sleep(1);
        }
        const unsigned* hRdG = hGc + (size_t)(tmax & 3) * HBUF;
        #pragma unroll
        for (int rr = 0; rr < 4; ++rr)
            gl_lds16(hRdG + (rr * 256 + tid) * 4, hS + (rr * 256 + tid) * 4);
        if (tid < 64) gl_lds16(hRdG + (1024 + tid) * 4, hS + (1024 + tid) * 4);
        __syncthreads();
        int s = tid >> 4, k0 = (tid & 15) * 16;
        float p = 0.f;
        #pragma unroll
        for (int m = 0; m < 16; ++m) {
            int u = k0 + m;
            unsigned pk = hS[s * HR + u];
            float hv = bf16f((short)(pk & 0xffffu)) + bf16f((short)(pk >> 16));
            p += linW[u] * hv;
        }
        p += __shfl_down(p, 8, 16);
        p += __shfl_down(p, 4, 16);
        p += __shfl_down(p, 2, 16);
        p += __shfl_down(p, 1, 16);
        if ((tid & 15) == 0) out[sid[s]] = p + linb[0];
    }
}

// ---------------------------------------------------------------------------
extern "C" void kernel_launch(void* const* d_in, const int* in_sizes, int n_in,
                              void* d_out, int out_size, void* d_ws, size_t ws_size,
                              hipStream_t stream) {
    const int*   tokens  = (const int*)d_in[0];
    const int*   icnt    = (const int*)d_in[1];
    const int*   tcnt    = (const int*)d_in[2];
    const float* emb     = (const float*)d_in[3];
    const float* Wih_tok = (const float*)d_in[4];
    const float* Whh_tok = (const float*)d_in[5];
    const float* b_tok   = (const float*)d_in[6];
    const float* Wih_ins = (const float*)d_in[7];
    const float* Whh_ins = (const float*)d_in[8];
    const float* b_ins   = (const float*)d_in[9];
    const float* linW    = (const float*)d_in[10];
    const float* linb    = (const float*)d_in[11];
    float* out = (float*)d_out;

    float* ws_f    = (float*)d_ws;
    float* Wih4t   = ws_f;                     // 262144 f
    float* b4t     = Wih4t + 262144;           // 1024 f
    float* b4i     = b4t + 1024;               // 1024 f
    int*   perm    = (int*)(b4i + 1024);       // 16384 i
    int*   perm2   = perm + 16384;             // 256 i
    int*   xcd_cnt = perm2 + 256;              // 8 i
    int*   flags   = xcd_cnt + 8;              // 16*65*8 = 8320 i
    int*   sync_end= flags + 8320;             // pad
    short* Bhi     = (short*)(sync_end + 376); // 4 x 262144 shorts (token frags)
    short* Blo     = Bhi + 262144;
    short* BXhi    = Blo + 262144;
    short* BXlo    = BXhi + 262144;
    short* B2h     = BXlo + 262144;            // 2 x 262144 shorts (instr slices)
    short* B2l     = B2h + 262144;
    unsigned* hG   = (unsigned*)(B2l + 262144); // 16*4*HBUF = 278528 uints
    float* Ep4     = (float*)(hG + 278528);    // 4194304 f
    float* Xp4     = Ep4 + 4194304;            // 16777216 f

    size_t need = ((char*)(Xp4 + 16777216)) - ((char*)d_ws);
    if (ws_size < need) return;  // fail loudly

    hipLaunchKernelGGL(k_pack, dim3(1024), dim3(256), 0, stream,
                       Wih_tok, b_tok, b_ins, Wih4t, b4t, b4i);
    hipLaunchKernelGGL(k_packB, dim3(64, 8), dim3(64), 0, stream,
                       Whh_tok, Wih_ins, Bhi, Blo, BXhi, BXlo);
    hipLaunchKernelGGL(k_packB2, dim3(64, 8), dim3(64), 0, stream,
                       Whh_ins, B2h, B2l);
    hipLaunchKernelGGL(k_sortn, dim3(1), dim3(1024), 0, stream, tcnt, perm, NSEQ, 17);
    hipLaunchKernelGGL(k_sortn, dim3(1), dim3(1024), 0, stream, icnt, perm2, Bq, 65);
    hipLaunchKernelGGL(k_zero, dim3(33), dim3(256), 0, stream, xcd_cnt, 8328);
    hipLaunchKernelGGL(k_zero, dim3(1088), dim3(256), 0, stream, (int*)hG, 278528);
    hipLaunchKernelGGL(k_epre, dim3(512), dim3(256), 0, stream,
                       emb, (const float4*)Wih4t, (const float4*)b4t, (float4*)Ep4);
    hipLaunchKernelGGL(k_token_mfma, dim3(512), dim3(512), 0, stream,
                       tokens, tcnt, perm, (const float4*)Ep4,
                       Bhi, Blo, BXhi, BXlo, (const float4*)b4i, (float4*)Xp4);
    hipLaunchKernelGGL(k_instr_xcd, dim3(256), dim3(256), 0, stream,
                       Xp4, icnt, perm2, B2h, B2l, xcd_cnt, flags, hG,
                       linW, linb, out);
}